// Round 4
// baseline (596.293 us; speedup 1.0000x reference)
//
#include <hip/hip_runtime.h>

// ---------------- types / helpers ----------------
typedef __bf16 bf16x8 __attribute__((ext_vector_type(8)));
typedef float f32x4 __attribute__((ext_vector_type(4)));
typedef unsigned short u16x8 __attribute__((ext_vector_type(8)));

__device__ __forceinline__ unsigned short f2bf(float f) {
  union { float f; unsigned int u; } v; v.f = f;
  unsigned int r = v.u + 0x7fffu + ((v.u >> 16) & 1u);  // RNE
  return (unsigned short)(r >> 16);
}

__device__ __forceinline__ void async16(const unsigned short* g, unsigned short* l) {
  __builtin_amdgcn_global_load_lds(
      (const __attribute__((address_space(1))) unsigned int*)g,
      (__attribute__((address_space(3))) unsigned int*)l, 16, 0, 0);
}

// ---------------- f32 -> bf16 convert (optional scale) ----------------
__global__ void cvt_bf16(const float* __restrict__ s, unsigned short* __restrict__ d, int n4,
                         float scale) {
  int i = blockIdx.x * 256 + threadIdx.x;
  if (i >= n4) return;
  float4 v = ((const float4*)s)[i];
  ushort4 o;
  o.x = f2bf(v.x * scale); o.y = f2bf(v.y * scale);
  o.z = f2bf(v.z * scale); o.w = f2bf(v.w * scale);
  ((ushort4*)d)[i] = o;
}

// ---------------- QKV bias concat (q pre-scaled) ----------------
__global__ void concat_bias(const float* __restrict__ qb, const float* __restrict__ kb,
                            const float* __restrict__ vb, float* __restrict__ o) {
  int i = blockIdx.x * 256 + threadIdx.x;  // 3072
  float v = (i < 1024) ? qb[i] * 0.125f : (i < 2048 ? kb[i - 1024] : vb[i - 2048]);
  o[i] = v;
}

// ---------------- LayerNorm (per 1024-row) -> bf16 ----------------
// PREFILL: also write dout[row] = src[row] + fbias (fc2 bias), for split-K atomic fc2.
template <int PREFILL>
__global__ __launch_bounds__(256) void ln_bf16(
    const float* __restrict__ src, unsigned short* __restrict__ dst,
    const float* __restrict__ g, const float* __restrict__ be,
    const float* __restrict__ fbias, float* __restrict__ dout) {
  const int row = blockIdx.x, tid = threadIdx.x;
  const float4 v = ((const float4*)(src + (size_t)row * 1024))[tid];
  if (PREFILL) {
    const float4 fb = ((const float4*)fbias)[tid];
    float4 r;
    r.x = v.x + fb.x; r.y = v.y + fb.y; r.z = v.z + fb.z; r.w = v.w + fb.w;
    ((float4*)(dout + (size_t)row * 1024))[tid] = r;
  }
  float s = v.x + v.y + v.z + v.w;
  float qq = v.x * v.x + v.y * v.y + v.z * v.z + v.w * v.w;
#pragma unroll
  for (int off = 32; off; off >>= 1) { s += __shfl_xor(s, off); qq += __shfl_xor(qq, off); }
  __shared__ float ps[4], pq[4];
  const int w = tid >> 6, lane = tid & 63;
  if (lane == 0) { ps[w] = s; pq[w] = qq; }
  __syncthreads();
  if (tid == 0) { ps[0] = ps[0] + ps[1] + ps[2] + ps[3]; pq[0] = pq[0] + pq[1] + pq[2] + pq[3]; }
  __syncthreads();
  const float mu = ps[0] * (1.f / 1024.f);
  const float var = pq[0] * (1.f / 1024.f) - mu * mu;
  const float rs = rsqrtf(var + 1e-5f);
  const float4 gv = ((const float4*)g)[tid];
  const float4 bv = ((const float4*)be)[tid];
  ushort4 o;
  o.x = f2bf((v.x - mu) * rs * gv.x + bv.x);
  o.y = f2bf((v.y - mu) * rs * gv.y + bv.y);
  o.z = f2bf((v.z - mu) * rs * gv.z + bv.z);
  o.w = f2bf((v.w - mu) * rs * gv.w + bv.w);
  ((ushort4*)(dst + (size_t)row * 1024))[tid] = o;
}

// ---------------- GEMM: C[M,N] = A[M,K] @ B[N,K]^T (+ bias), m97-style ----------------
// EPI: 2 = acc+bias+resid -> f32 ; 3 = relu(acc+bias) -> bf16 ;
//      5 = fused QKV epilogue -> head-major bf16 (Cout = QB base; K/V at fixed offsets) ;
//      6 = atomicAdd(Cout, acc) f32 (split-K partial via blockIdx.z, bias pre-applied elsewhere)
#define KOFF 6291456ull
#define VOFF 13631488ull
template <int EPI>
__global__ __launch_bounds__(256) void gemm_bt(
    const unsigned short* __restrict__ A, const unsigned short* __restrict__ Bw,
    const float* __restrict__ bias, const float* __restrict__ resid,
    void* __restrict__ Cout, int M, int N, int K, int lda, int ldb) {
  __shared__ __align__(16) unsigned short lA[128 * 32];
  __shared__ __align__(16) unsigned short lB[128 * 32];
  const int tid = threadIdx.x;
  const int w = tid >> 6, lane = tid & 63;
  const int lr = lane & 15, lq = lane >> 4;
  const int bm = blockIdx.y, bn = blockIdx.x;
  const size_t koff = (size_t)blockIdx.z * K;  // split-K offset (z=0 when gridDim.z==1)
  const unsigned short* Ab = A + (size_t)bm * 128 * lda + koff;
  const unsigned short* Bb = Bw + (size_t)bn * 128 * ldb + koff;
  const int wm = (w & 1) << 6, wn = (w >> 1) << 6;
  f32x4 acc[4][4] = {};
  const int kiters = K >> 5;
  const int c0 = tid, c1 = 256 + tid;
  const int r0 = c0 >> 2, o0 = (c0 & 3) << 3;
  const int r1 = c1 >> 2, o1 = (c1 & 3) << 3;
  for (int kt = 0; kt < kiters; ++kt) {
    const int kb = kt << 5;
    __syncthreads();
    async16(Ab + (size_t)r0 * lda + kb + o0, lA + c0 * 8);
    async16(Bb + (size_t)r0 * ldb + kb + o0, lB + c0 * 8);
    async16(Ab + (size_t)r1 * lda + kb + o1, lA + c1 * 8);
    async16(Bb + (size_t)r1 * ldb + kb + o1, lB + c1 * 8);
    __syncthreads();
    bf16x8 af[4], bfr[4];
#pragma unroll
    for (int i = 0; i < 4; ++i) af[i] = *(const bf16x8*)(lA + (wm + i * 16 + lr) * 32 + lq * 8);
#pragma unroll
    for (int i = 0; i < 4; ++i) bfr[i] = *(const bf16x8*)(lB + (wn + i * 16 + lr) * 32 + lq * 8);
#pragma unroll
    for (int i = 0; i < 4; ++i)
#pragma unroll
      for (int j = 0; j < 4; ++j)
        acc[i][j] = __builtin_amdgcn_mfma_f32_16x16x32_bf16(af[i], bfr[j], acc[i][j], 0, 0, 0);
  }
  const int which = (bn * 128) >> 10;  // EPI5: 0=Q,1=K,2=V (block-uniform; 1024%128==0)
#pragma unroll
  for (int i = 0; i < 4; ++i) {
#pragma unroll
    for (int j = 0; j < 4; ++j) {
      const int colg = bn * 128 + wn + j * 16 + lr;
      const float bi = (EPI == 6) ? 0.f : bias[colg];
      const int rowg0 = bm * 128 + wm + i * 16 + lq * 4;
#pragma unroll
      for (int r = 0; r < 4; ++r) {
        const int rowg = rowg0 + r;
        const float val = acc[i][j][r] + bi;
        if (EPI == 5) {
          const int t = rowg >> 4, bb = rowg & 15;
          const int hh = (colg >> 6) & 15, dd = colg & 63;
          const size_t nn = (size_t)(bb * 16 + hh);
          unsigned short* q16 = (unsigned short*)Cout;
          if (which == 0) {
            if (rowg >= 1024) q16[(nn * 384 + (t - 64)) * 64 + dd] = f2bf(val);
          } else if (which == 1) {
            q16[KOFF + (nn * 448 + t) * 64 + dd] = f2bf(val);
          } else {
            q16[VOFF + (nn * 448 + t) * 64 + dd] = f2bf(val);
          }
        } else {
          const size_t idx = (size_t)rowg * N + colg;
          if (EPI == 2) ((float*)Cout)[idx] = val + resid[idx];
          else if (EPI == 3) ((unsigned short*)Cout)[idx] = f2bf(fmaxf(val, 0.f));
          else if (EPI == 6) atomicAdd(&((float*)Cout)[idx], acc[i][j][r]);
        }
      }
    }
  }
}

// ---------------- V transpose: vb[n][t][d] -> vt[n][d][t] ----------------
__global__ __launch_bounds__(256) void vtrans(const unsigned short* __restrict__ vb,
                                              unsigned short* __restrict__ vt) {
  __shared__ __align__(16) unsigned short ls[64][80];
  const int kc = blockIdx.x, n = blockIdx.y;
  const int tid = threadIdx.x;
#pragma unroll
  for (int i = 0; i < 2; ++i) {
    const int c = i * 256 + tid;
    const int kk = c >> 3, dc = (c & 7) << 3;
    u16x8 val = *(const u16x8*)(vb + ((size_t)n * 448 + kc * 64 + kk) * 64 + dc);
    *(u16x8*)&ls[kk][dc] = val;
  }
  __syncthreads();
#pragma unroll
  for (int i = 0; i < 2; ++i) {
    const int c = i * 256 + tid;
    const int d = c >> 3, kx = (c & 7) << 3;
    u16x8 o;
#pragma unroll
    for (int j = 0; j < 8; ++j) o[j] = ls[kx + j][d];
    *(u16x8*)(vt + ((size_t)n * 64 + d) * 448 + kc * 64 + kx) = o;
  }
}

// ---------------- fused attention, S^T formulation ----------------
// One wave (64 threads) per (head, 16 q-rows). Grid 6144 = 8 XCD x 32 heads x 24 qtiles.
// S^T via mfma(A=K, B=Q): each lane holds 112 k-scores of ONE q-row (lr) in regs ->
// softmax/suppression reductions are in-register + 2 shuffle stages (xor 16, 32).
// P staged to wave-private LDS (bf16) as the PV^T B-operand; out^T transposed via LDS alias.
#define PST 468  // P row stride (u16): dword stride 234 == 10 mod 32 -> ~2-way (free)
__global__ __launch_bounds__(64, 3) void attn_kernel(
    const unsigned short* __restrict__ qt_, const unsigned short* __restrict__ kt_,
    const unsigned short* __restrict__ vt_, unsigned short* __restrict__ attn) {
  __shared__ __align__(16) unsigned short P[16 * PST];  // 14976 B -> ~10 blocks/CU
  const int id = blockIdx.x;
  const int xcd = id & 7, j0 = id >> 3;
  const int n = xcd * 32 + (j0 & 31), qt = j0 >> 5;  // qt 0..23
  const int b = n >> 4, h = n & 15;
  const int lane = threadIdx.x;
  const int lr = lane & 15, lq = lane >> 4;

  // Q fragments (B-operand: B[d][q], lane q=lr holds Q[q][lq*8..+8])
  const unsigned short* qp = qt_ + ((size_t)n * 384 + qt * 16 + lr) * 64 + lq * 8;
  const bf16x8 q0 = *(const bf16x8*)qp;
  const bf16x8 q1 = *(const bf16x8*)(qp + 32);

  // phase 1: S^T[k][q] accumulators. acc[t][r] = S[q=lr][k = 16t + 4lq + r]
  f32x4 acc[28];
#pragma unroll
  for (int t = 0; t < 28; ++t) {
    const unsigned short* kp = kt_ + ((size_t)n * 448 + t * 16 + lr) * 64 + lq * 8;
    const bf16x8 k0 = *(const bf16x8*)kp;
    const bf16x8 k1 = *(const bf16x8*)(kp + 32);
    f32x4 a = {0.f, 0.f, 0.f, 0.f};
    a = __builtin_amdgcn_mfma_f32_16x16x32_bf16(k0, q0, a, 0, 0, 0);
    a = __builtin_amdgcn_mfma_f32_16x16x32_bf16(k1, q1, a, 0, 0, 0);
    acc[t] = a;
  }

  // phase 2: per-row softmax + suppression + re-softmax. Row = lr, shared by 4 lanes (lq).
  // max
  f32x4 m4 = acc[0];
#pragma unroll
  for (int t = 1; t < 28; ++t) {
    m4[0] = fmaxf(m4[0], acc[t][0]); m4[1] = fmaxf(m4[1], acc[t][1]);
    m4[2] = fmaxf(m4[2], acc[t][2]); m4[3] = fmaxf(m4[3], acc[t][3]);
  }
  float m = fmaxf(fmaxf(m4[0], m4[1]), fmaxf(m4[2], m4[3]));
  m = fmaxf(m, __shfl_xor(m, 16));
  m = fmaxf(m, __shfl_xor(m, 32));
  // exp (in place), sum, count(e>0)
  f32x4 s4 = {0.f, 0.f, 0.f, 0.f}, c4 = {0.f, 0.f, 0.f, 0.f};
#pragma unroll
  for (int t = 0; t < 28; ++t) {
#pragma unroll
    for (int r = 0; r < 4; ++r) {
      const float e = __expf(acc[t][r] - m);
      acc[t][r] = e;
      s4[r] += e;
      if (e > 0.f) c4[r] += 1.f;
    }
  }
  float s = (s4[0] + s4[1]) + (s4[2] + s4[3]);
  float cnt = (c4[0] + c4[1]) + (c4[2] + c4[3]);
  s += __shfl_xor(s, 16); s += __shfl_xor(s, 32);
  cnt += __shfl_xor(cnt, 16); cnt += __shfl_xor(cnt, 32);
  const float inv = 1.f / s;
  const float mean = 1.f / cnt;  // sum(p) == 1
  // variance of p over nonzeros
  f32x4 d4 = {0.f, 0.f, 0.f, 0.f};
#pragma unroll
  for (int t = 0; t < 28; ++t) {
#pragma unroll
    for (int r = 0; r < 4; ++r) {
      const float p = acc[t][r] * inv;
      const float dd = p - mean;
      if (acc[t][r] > 0.f) d4[r] += dd * dd;
    }
  }
  float dv = (d4[0] + d4[1]) + (d4[2] + d4[3]);
  dv += __shfl_xor(dv, 16); dv += __shfl_xor(dv, 32);
  const float thr = mean - 0.5f * sqrtf(dv / (cnt - 1.f));
  // renormalizer over survivors (row max always survives -> same max, reuse e)
  f32x4 t4 = {0.f, 0.f, 0.f, 0.f};
#pragma unroll
  for (int t = 0; t < 28; ++t) {
#pragma unroll
    for (int r = 0; r < 4; ++r) {
      if (!(acc[t][r] * inv < thr)) t4[r] += acc[t][r];
    }
  }
  float s2 = (t4[0] + t4[1]) + (t4[2] + t4[3]);
  s2 += __shfl_xor(s2, 16); s2 += __shfl_xor(s2, 32);
  const float inv2 = 1.f / s2;

  // write P[q=lr][k] bf16 to LDS (b32-packed pairs; dword banks ~2-way)
#pragma unroll
  for (int t = 0; t < 28; ++t) {
#pragma unroll
    for (int rp = 0; rp < 4; rp += 2) {
      const float v0 = (acc[t][rp] * inv < thr) ? 0.f : acc[t][rp] * inv2;
      const float v1 = (acc[t][rp + 1] * inv < thr) ? 0.f : acc[t][rp + 1] * inv2;
      const unsigned int u = (unsigned int)f2bf(v0) | ((unsigned int)f2bf(v1) << 16);
      *(unsigned int*)&P[lr * PST + t * 16 + lq * 4 + rp] = u;
    }
  }
  __syncthreads();  // single wave: just drains lgkmcnt

  // phase 3: out^T[d][q] = V^T(64x448) . P(448x16). A = VT rows (coalesced), B = P from LDS.
  f32x4 o[4] = {};
#pragma unroll
  for (int c = 0; c < 14; ++c) {
    union { ushort4 h[2]; bf16x8 v; } bf;
    bf.h[0] = *(const ushort4*)&P[lr * PST + c * 32 + lq * 8];
    bf.h[1] = *(const ushort4*)&P[lr * PST + c * 32 + lq * 8 + 4];
    bf16x8 a[4];
#pragma unroll
    for (int dt = 0; dt < 4; ++dt)
      a[dt] = *(const bf16x8*)(vt_ + ((size_t)n * 64 + dt * 16 + lr) * 448 + c * 32 + lq * 8);
#pragma unroll
    for (int dt = 0; dt < 4; ++dt)
      o[dt] = __builtin_amdgcn_mfma_f32_16x16x32_bf16(a[dt], bf.v, o[dt], 0, 0, 0);
  }
  __syncthreads();  // P reads done; alias region below

  // transpose out^T via LDS (stride-17 dwords), then coalesced bf16 store
  float* OT = (float*)P;
#pragma unroll
  for (int dt = 0; dt < 4; ++dt)
#pragma unroll
    for (int r = 0; r < 4; ++r)
      OT[(dt * 16 + lq * 4 + r) * 17 + lr] = o[dt][r];
  __syncthreads();
  const int qrow = lane >> 2, dg = lane & 3;
  union { unsigned short u[16]; u16x8 v[2]; } ov;
#pragma unroll
  for (int jj = 0; jj < 16; ++jj) ov.u[jj] = f2bf(OT[(dg * 16 + jj) * 17 + qrow]);
  unsigned short* op = attn + ((size_t)(qt * 16 + qrow) * 16 + b) * 1024 + h * 64 + dg * 16;
  *(u16x8*)op = ov.v[0];
  *(u16x8*)(op + 8) = ov.v[1];
}

// ---------------- launch ----------------
extern "C" void kernel_launch(void* const* d_in, const int* in_sizes, int n_in,
                              void* d_out, int out_size, void* d_ws, size_t ws_size,
                              hipStream_t stream) {
  (void)in_sizes; (void)n_in; (void)out_size; (void)ws_size;
  const float* x    = (const float*)d_in[0];
  const float* mem  = (const float*)d_in[1];
  const float* q_w  = (const float*)d_in[2];
  const float* q_b  = (const float*)d_in[3];
  const float* k_w  = (const float*)d_in[4];
  const float* k_b  = (const float*)d_in[5];
  const float* v_w  = (const float*)d_in[6];
  const float* v_b  = (const float*)d_in[7];
  const float* o_w  = (const float*)d_in[8];
  const float* o_b  = (const float*)d_in[9];
  const float* ln1w = (const float*)d_in[10];
  const float* ln1b = (const float*)d_in[11];
  const float* f1w  = (const float*)d_in[12];
  const float* f1b  = (const float*)d_in[13];
  const float* f2w  = (const float*)d_in[14];
  const float* f2b  = (const float*)d_in[15];
  const float* ln2w = (const float*)d_in[16];
  const float* ln2b = (const float*)d_in[17];

  unsigned short* WQ   = (unsigned short*)d_ws;        // 3x 1048576 contiguous = fused B
  unsigned short* WK   = WQ + 1048576;
  unsigned short* WV   = WK + 1048576;
  unsigned short* WO   = WV + 1048576;
  unsigned short* WF1  = WO + 1048576;                 // 4194304
  unsigned short* WF2  = WF1 + 4194304;                // 4194304
  unsigned short* ABUF = WF2 + 4194304;                // 7340032 (mem rows 0..1023, xn rows 1024..7167)
  unsigned short* QB   = ABUF + 7340032;               // 6291456 [n][384][64]; KB/VB at KOFF/VOFF
  unsigned short* KB   = QB + 6291456;                 // 7340032 [n][448][64]
  unsigned short* VB   = KB + 7340032;                 // 7340032 [n][448][64]
  unsigned short* VT   = VB + 7340032;                 // 7340032 [n][64][448]
  unsigned short* ATTN = VT + 7340032;                 // 6291456
  float*          X2   = (float*)(ATTN + 6291456);     // 6291456 f32
  float*          QKVB = (float*)ATTN;                 // 3072 f32, dead before attn writes ATTN
  unsigned short* XN2  = ATTN;                         // alias (attn dead after out-proj)
  unsigned short* HB   = ABUF;                         // alias (A/q/k/v staging dead after attention)

  // weight + memory converts (0.125 q-scale folded into weights+bias)
  cvt_bf16<<<1024, 256, 0, stream>>>(q_w, WQ, 262144, 0.125f);
  cvt_bf16<<<1024, 256, 0, stream>>>(k_w, WK, 262144, 1.f);
  cvt_bf16<<<1024, 256, 0, stream>>>(v_w, WV, 262144, 1.f);
  cvt_bf16<<<1024, 256, 0, stream>>>(o_w, WO, 262144, 1.f);
  cvt_bf16<<<4096, 256, 0, stream>>>(f1w, WF1, 1048576, 1.f);
  cvt_bf16<<<4096, 256, 0, stream>>>(f2w, WF2, 1048576, 1.f);
  cvt_bf16<<<1024, 256, 0, stream>>>(mem, ABUF, 262144, 1.f);
  concat_bias<<<12, 256, 0, stream>>>(q_b, k_b, v_b, QKVB);

  // LN1 -> xn (rows 1024.. of ABUF)
  ln_bf16<0><<<6144, 256, 0, stream>>>(x, ABUF + 1048576, ln1w, ln1b, nullptr, nullptr);

  // fused QKV: [mem;xn] x [Wq;Wk;Wv]^T, head-major epilogue (summary row is dead code)
  gemm_bt<5><<<dim3(24, 56), 256, 0, stream>>>(ABUF, WQ, QKVB, nullptr, QB, 7168, 3072, 1024, 1024, 1024);

  vtrans<<<dim3(7, 256), 256, 0, stream>>>(VB, VT);
  attn_kernel<<<6144, 64, 0, stream>>>(QB, KB, VT, ATTN);

  // out-proj + residual -> X2 (f32)
  gemm_bt<2><<<dim3(8, 48), 256, 0, stream>>>(ATTN, WO, o_b, x, X2, 6144, 1024, 1024, 1024, 1024);

  // LN2 -> xn2, and prefill d_out = X2 + fc2_bias (for split-K atomic fc2)
  ln_bf16<1><<<6144, 256, 0, stream>>>(X2, XN2, ln2w, ln2b, f2b, (float*)d_out);

  // FFN
  gemm_bt<3><<<dim3(32, 48), 256, 0, stream>>>(XN2, WF1, f1b, nullptr, HB, 6144, 4096, 1024, 1024, 1024);
  // fc2 split-K=2 in ONE dispatch (grid.z): 768 concurrent blocks, atomics into prefilled d_out
  gemm_bt<6><<<dim3(8, 48, 2), 256, 0, stream>>>(HB, WF2, nullptr, nullptr, d_out, 6144, 1024, 2048, 4096, 4096);
}

// Round 5
// 578.830 us; speedup vs baseline: 1.0302x; 1.0302x over previous
//
#include <hip/hip_runtime.h>

// ---------------- types / helpers ----------------
typedef __bf16 bf16x8 __attribute__((ext_vector_type(8)));
typedef float f32x4 __attribute__((ext_vector_type(4)));
typedef unsigned short u16x8 __attribute__((ext_vector_type(8)));

__device__ __forceinline__ unsigned short f2bf(float f) {
  union { float f; unsigned int u; } v; v.f = f;
  unsigned int r = v.u + 0x7fffu + ((v.u >> 16) & 1u);  // RNE
  return (unsigned short)(r >> 16);
}

__device__ __forceinline__ void async16(const unsigned short* g, unsigned short* l) {
  __builtin_amdgcn_global_load_lds(
      (const __attribute__((address_space(1))) unsigned int*)g,
      (__attribute__((address_space(3))) unsigned int*)l, 16, 0, 0);
}

// ---------------- f32 -> bf16 convert (optional scale) ----------------
__global__ void cvt_bf16(const float* __restrict__ s, unsigned short* __restrict__ d, int n4,
                         float scale) {
  int i = blockIdx.x * 256 + threadIdx.x;
  if (i >= n4) return;
  float4 v = ((const float4*)s)[i];
  ushort4 o;
  o.x = f2bf(v.x * scale); o.y = f2bf(v.y * scale);
  o.z = f2bf(v.z * scale); o.w = f2bf(v.w * scale);
  ((ushort4*)d)[i] = o;
}

// ---------------- QKV bias concat (q pre-scaled) ----------------
__global__ void concat_bias(const float* __restrict__ qb, const float* __restrict__ kb,
                            const float* __restrict__ vb, float* __restrict__ o) {
  int i = blockIdx.x * 256 + threadIdx.x;  // 3072
  float v = (i < 1024) ? qb[i] * 0.125f : (i < 2048 ? kb[i - 1024] : vb[i - 2048]);
  o[i] = v;
}

// ---------------- LayerNorm (per 1024-row) -> bf16 ----------------
// PREFILL: also write dout[row] = src[row] + fbias (fc2 bias), for split-K atomic fc2.
template <int PREFILL>
__global__ __launch_bounds__(256) void ln_bf16(
    const float* __restrict__ src, unsigned short* __restrict__ dst,
    const float* __restrict__ g, const float* __restrict__ be,
    const float* __restrict__ fbias, float* __restrict__ dout) {
  const int row = blockIdx.x, tid = threadIdx.x;
  const float4 v = ((const float4*)(src + (size_t)row * 1024))[tid];
  if (PREFILL) {
    const float4 fb = ((const float4*)fbias)[tid];
    float4 r;
    r.x = v.x + fb.x; r.y = v.y + fb.y; r.z = v.z + fb.z; r.w = v.w + fb.w;
    ((float4*)(dout + (size_t)row * 1024))[tid] = r;
  }
  float s = v.x + v.y + v.z + v.w;
  float qq = v.x * v.x + v.y * v.y + v.z * v.z + v.w * v.w;
#pragma unroll
  for (int off = 32; off; off >>= 1) { s += __shfl_xor(s, off); qq += __shfl_xor(qq, off); }
  __shared__ float ps[4], pq[4];
  const int w = tid >> 6, lane = tid & 63;
  if (lane == 0) { ps[w] = s; pq[w] = qq; }
  __syncthreads();
  if (tid == 0) { ps[0] = ps[0] + ps[1] + ps[2] + ps[3]; pq[0] = pq[0] + pq[1] + pq[2] + pq[3]; }
  __syncthreads();
  const float mu = ps[0] * (1.f / 1024.f);
  const float var = pq[0] * (1.f / 1024.f) - mu * mu;
  const float rs = rsqrtf(var + 1e-5f);
  const float4 gv = ((const float4*)g)[tid];
  const float4 bv = ((const float4*)be)[tid];
  ushort4 o;
  o.x = f2bf((v.x - mu) * rs * gv.x + bv.x);
  o.y = f2bf((v.y - mu) * rs * gv.y + bv.y);
  o.z = f2bf((v.z - mu) * rs * gv.z + bv.z);
  o.w = f2bf((v.w - mu) * rs * gv.w + bv.w);
  ((ushort4*)(dst + (size_t)row * 1024))[tid] = o;
}

// ---------------- GEMM: C[M,N] = A[M,K] @ B[N,K]^T (+ bias), m97-style ----------------
// EPI: 2 = acc+bias+resid -> f32 ; 3 = relu(acc+bias) -> bf16 ;
//      5 = fused QKV epilogue -> head-major bf16 (Cout = QB base; K/V at fixed offsets) ;
//      6 = atomicAdd(Cout, acc) f32 (split-K partial via blockIdx.z, bias pre-applied elsewhere)
#define KOFF 6291456ull
#define VOFF 13631488ull
template <int EPI>
__global__ __launch_bounds__(256) void gemm_bt(
    const unsigned short* __restrict__ A, const unsigned short* __restrict__ Bw,
    const float* __restrict__ bias, const float* __restrict__ resid,
    void* __restrict__ Cout, int M, int N, int K, int lda, int ldb) {
  __shared__ __align__(16) unsigned short lA[128 * 32];
  __shared__ __align__(16) unsigned short lB[128 * 32];
  const int tid = threadIdx.x;
  const int w = tid >> 6, lane = tid & 63;
  const int lr = lane & 15, lq = lane >> 4;
  const int bm = blockIdx.y, bn = blockIdx.x;
  const size_t koff = (size_t)blockIdx.z * K;  // split-K offset (z=0 when gridDim.z==1)
  const unsigned short* Ab = A + (size_t)bm * 128 * lda + koff;
  const unsigned short* Bb = Bw + (size_t)bn * 128 * ldb + koff;
  const int wm = (w & 1) << 6, wn = (w >> 1) << 6;
  f32x4 acc[4][4] = {};
  const int kiters = K >> 5;
  const int c0 = tid, c1 = 256 + tid;
  const int r0 = c0 >> 2, o0 = (c0 & 3) << 3;
  const int r1 = c1 >> 2, o1 = (c1 & 3) << 3;
  for (int kt = 0; kt < kiters; ++kt) {
    const int kb = kt << 5;
    __syncthreads();
    async16(Ab + (size_t)r0 * lda + kb + o0, lA + c0 * 8);
    async16(Bb + (size_t)r0 * ldb + kb + o0, lB + c0 * 8);
    async16(Ab + (size_t)r1 * lda + kb + o1, lA + c1 * 8);
    async16(Bb + (size_t)r1 * ldb + kb + o1, lB + c1 * 8);
    __syncthreads();
    bf16x8 af[4], bfr[4];
#pragma unroll
    for (int i = 0; i < 4; ++i) af[i] = *(const bf16x8*)(lA + (wm + i * 16 + lr) * 32 + lq * 8);
#pragma unroll
    for (int i = 0; i < 4; ++i) bfr[i] = *(const bf16x8*)(lB + (wn + i * 16 + lr) * 32 + lq * 8);
#pragma unroll
    for (int i = 0; i < 4; ++i)
#pragma unroll
      for (int j = 0; j < 4; ++j)
        acc[i][j] = __builtin_amdgcn_mfma_f32_16x16x32_bf16(af[i], bfr[j], acc[i][j], 0, 0, 0);
  }
  const int which = (bn * 128) >> 10;  // EPI5: 0=Q,1=K,2=V (block-uniform; 1024%128==0)
#pragma unroll
  for (int i = 0; i < 4; ++i) {
#pragma unroll
    for (int j = 0; j < 4; ++j) {
      const int colg = bn * 128 + wn + j * 16 + lr;
      const float bi = (EPI == 6) ? 0.f : bias[colg];
      const int rowg0 = bm * 128 + wm + i * 16 + lq * 4;
#pragma unroll
      for (int r = 0; r < 4; ++r) {
        const int rowg = rowg0 + r;
        const float val = acc[i][j][r] + bi;
        if (EPI == 5) {
          const int t = rowg >> 4, bb = rowg & 15;
          const int hh = (colg >> 6) & 15, dd = colg & 63;
          const size_t nn = (size_t)(bb * 16 + hh);
          unsigned short* q16 = (unsigned short*)Cout;
          if (which == 0) {
            if (rowg >= 1024) q16[(nn * 384 + (t - 64)) * 64 + dd] = f2bf(val);
          } else if (which == 1) {
            q16[KOFF + (nn * 448 + t) * 64 + dd] = f2bf(val);
          } else {
            q16[VOFF + (nn * 448 + t) * 64 + dd] = f2bf(val);
          }
        } else {
          const size_t idx = (size_t)rowg * N + colg;
          if (EPI == 2) ((float*)Cout)[idx] = val + resid[idx];
          else if (EPI == 3) ((unsigned short*)Cout)[idx] = f2bf(fmaxf(val, 0.f));
          else if (EPI == 6) atomicAdd(&((float*)Cout)[idx], acc[i][j][r]);
        }
      }
    }
  }
}

// ---------------- V transpose: vb[n][t][d] -> vt[n][d][t] ----------------
__global__ __launch_bounds__(256) void vtrans(const unsigned short* __restrict__ vb,
                                              unsigned short* __restrict__ vt) {
  __shared__ __align__(16) unsigned short ls[64][80];
  const int kc = blockIdx.x, n = blockIdx.y;
  const int tid = threadIdx.x;
#pragma unroll
  for (int i = 0; i < 2; ++i) {
    const int c = i * 256 + tid;
    const int kk = c >> 3, dc = (c & 7) << 3;
    u16x8 val = *(const u16x8*)(vb + ((size_t)n * 448 + kc * 64 + kk) * 64 + dc);
    *(u16x8*)&ls[kk][dc] = val;
  }
  __syncthreads();
#pragma unroll
  for (int i = 0; i < 2; ++i) {
    const int c = i * 256 + tid;
    const int d = c >> 3, kx = (c & 7) << 3;
    u16x8 o;
#pragma unroll
    for (int j = 0; j < 8; ++j) o[j] = ls[kx + j][d];
    *(u16x8*)(vt + ((size_t)n * 64 + d) * 448 + kc * 64 + kx) = o;
  }
}

// ---------------- fused attention, S^T formulation ----------------
// One wave (64 threads) per (head, 16 q-rows). Grid 6144 = 8 XCD x 32 heads x 24 qtiles.
// S^T via mfma(A=K, B=Q): each lane holds 112 k-scores of ONE q-row (lr) in regs ->
// softmax/suppression reductions are in-register + 2 shuffle stages (xor 16, 32).
// NOTE: no waves-per-EU clamp! acc[28] needs ~165 VGPRs; clamping to 3 waves/EU (r4)
// spilled the whole score array to scratch (157 MB WRITE_SIZE, 146 us).
#define PST 468  // P row stride (u16): dword stride 234 == 10 mod 32 -> ~2-way (free)
__global__ __launch_bounds__(64) void attn_kernel(
    const unsigned short* __restrict__ qt_, const unsigned short* __restrict__ kt_,
    const unsigned short* __restrict__ vt_, unsigned short* __restrict__ attn) {
  __shared__ __align__(16) unsigned short P[16 * PST];  // 14976 B
  const int id = blockIdx.x;
  const int xcd = id & 7, j0 = id >> 3;
  const int n = xcd * 32 + (j0 & 31), qt = j0 >> 5;  // qt 0..23
  const int b = n >> 4, h = n & 15;
  const int lane = threadIdx.x;
  const int lr = lane & 15, lq = lane >> 4;

  // Q fragments (B-operand: B[d][q], lane q=lr holds Q[q][lq*8..+8])
  const unsigned short* qp = qt_ + ((size_t)n * 384 + qt * 16 + lr) * 64 + lq * 8;
  const bf16x8 q0 = *(const bf16x8*)qp;
  const bf16x8 q1 = *(const bf16x8*)(qp + 32);

  // phase 1: S^T[k][q] accumulators. acc[t][r] = S[q=lr][k = 16t + 4lq + r]
  f32x4 acc[28];
#pragma unroll
  for (int t = 0; t < 28; ++t) {
    const unsigned short* kp = kt_ + ((size_t)n * 448 + t * 16 + lr) * 64 + lq * 8;
    const bf16x8 k0 = *(const bf16x8*)kp;
    const bf16x8 k1 = *(const bf16x8*)(kp + 32);
    f32x4 a = {0.f, 0.f, 0.f, 0.f};
    a = __builtin_amdgcn_mfma_f32_16x16x32_bf16(k0, q0, a, 0, 0, 0);
    a = __builtin_amdgcn_mfma_f32_16x16x32_bf16(k1, q1, a, 0, 0, 0);
    acc[t] = a;
  }

  // phase 2: per-row softmax + suppression + re-softmax. Row = lr, shared by 4 lanes (lq).
  // max
  f32x4 m4 = acc[0];
#pragma unroll
  for (int t = 1; t < 28; ++t) {
    m4[0] = fmaxf(m4[0], acc[t][0]); m4[1] = fmaxf(m4[1], acc[t][1]);
    m4[2] = fmaxf(m4[2], acc[t][2]); m4[3] = fmaxf(m4[3], acc[t][3]);
  }
  float m = fmaxf(fmaxf(m4[0], m4[1]), fmaxf(m4[2], m4[3]));
  m = fmaxf(m, __shfl_xor(m, 16));
  m = fmaxf(m, __shfl_xor(m, 32));
  // exp (in place), sum, count(e>0)
  f32x4 s4 = {0.f, 0.f, 0.f, 0.f}, c4 = {0.f, 0.f, 0.f, 0.f};
#pragma unroll
  for (int t = 0; t < 28; ++t) {
#pragma unroll
    for (int r = 0; r < 4; ++r) {
      const float e = __expf(acc[t][r] - m);
      acc[t][r] = e;
      s4[r] += e;
      if (e > 0.f) c4[r] += 1.f;
    }
  }
  float s = (s4[0] + s4[1]) + (s4[2] + s4[3]);
  float cnt = (c4[0] + c4[1]) + (c4[2] + c4[3]);
  s += __shfl_xor(s, 16); s += __shfl_xor(s, 32);
  cnt += __shfl_xor(cnt, 16); cnt += __shfl_xor(cnt, 32);
  const float inv = 1.f / s;
  const float mean = 1.f / cnt;  // sum(p) == 1
  // variance of p over nonzeros
  f32x4 d4 = {0.f, 0.f, 0.f, 0.f};
#pragma unroll
  for (int t = 0; t < 28; ++t) {
#pragma unroll
    for (int r = 0; r < 4; ++r) {
      const float p = acc[t][r] * inv;
      const float dd = p - mean;
      if (acc[t][r] > 0.f) d4[r] += dd * dd;
    }
  }
  float dv = (d4[0] + d4[1]) + (d4[2] + d4[3]);
  dv += __shfl_xor(dv, 16); dv += __shfl_xor(dv, 32);
  const float thr = mean - 0.5f * sqrtf(dv / (cnt - 1.f));
  // renormalizer over survivors (row max always survives -> same max, reuse e)
  f32x4 t4 = {0.f, 0.f, 0.f, 0.f};
#pragma unroll
  for (int t = 0; t < 28; ++t) {
#pragma unroll
    for (int r = 0; r < 4; ++r) {
      if (!(acc[t][r] * inv < thr)) t4[r] += acc[t][r];
    }
  }
  float s2 = (t4[0] + t4[1]) + (t4[2] + t4[3]);
  s2 += __shfl_xor(s2, 16); s2 += __shfl_xor(s2, 32);
  const float inv2 = 1.f / s2;

  // write P[q=lr][k] bf16 to LDS (b32-packed pairs; dword banks ~2-way)
#pragma unroll
  for (int t = 0; t < 28; ++t) {
#pragma unroll
    for (int rp = 0; rp < 4; rp += 2) {
      const float v0 = (acc[t][rp] * inv < thr) ? 0.f : acc[t][rp] * inv2;
      const float v1 = (acc[t][rp + 1] * inv < thr) ? 0.f : acc[t][rp + 1] * inv2;
      const unsigned int u = (unsigned int)f2bf(v0) | ((unsigned int)f2bf(v1) << 16);
      *(unsigned int*)&P[lr * PST + t * 16 + lq * 4 + rp] = u;
    }
  }
  __syncthreads();  // single wave: just drains lgkmcnt

  // phase 3: out^T[d][q] = V^T(64x448) . P(448x16). A = VT rows (coalesced), B = P from LDS.
  f32x4 o[4] = {};
#pragma unroll
  for (int c = 0; c < 14; ++c) {
    union { ushort4 h[2]; bf16x8 v; } bf;
    bf.h[0] = *(const ushort4*)&P[lr * PST + c * 32 + lq * 8];
    bf.h[1] = *(const ushort4*)&P[lr * PST + c * 32 + lq * 8 + 4];
    bf16x8 a[4];
#pragma unroll
    for (int dt = 0; dt < 4; ++dt)
      a[dt] = *(const bf16x8*)(vt_ + ((size_t)n * 64 + dt * 16 + lr) * 448 + c * 32 + lq * 8);
#pragma unroll
    for (int dt = 0; dt < 4; ++dt)
      o[dt] = __builtin_amdgcn_mfma_f32_16x16x32_bf16(a[dt], bf.v, o[dt], 0, 0, 0);
  }
  __syncthreads();  // P reads done; alias region below

  // transpose out^T via LDS (stride-17 dwords), then coalesced bf16 store
  float* OT = (float*)P;
#pragma unroll
  for (int dt = 0; dt < 4; ++dt)
#pragma unroll
    for (int r = 0; r < 4; ++r)
      OT[(dt * 16 + lq * 4 + r) * 17 + lr] = o[dt][r];
  __syncthreads();
  const int qrow = lane >> 2, dg = lane & 3;
  union { unsigned short u[16]; u16x8 v[2]; } ov;
#pragma unroll
  for (int jj = 0; jj < 16; ++jj) ov.u[jj] = f2bf(OT[(dg * 16 + jj) * 17 + qrow]);
  unsigned short* op = attn + ((size_t)(qt * 16 + qrow) * 16 + b) * 1024 + h * 64 + dg * 16;
  *(u16x8*)op = ov.v[0];
  *(u16x8*)(op + 8) = ov.v[1];
}

// ---------------- launch ----------------
extern "C" void kernel_launch(void* const* d_in, const int* in_sizes, int n_in,
                              void* d_out, int out_size, void* d_ws, size_t ws_size,
                              hipStream_t stream) {
  (void)in_sizes; (void)n_in; (void)out_size; (void)ws_size;
  const float* x    = (const float*)d_in[0];
  const float* mem  = (const float*)d_in[1];
  const float* q_w  = (const float*)d_in[2];
  const float* q_b  = (const float*)d_in[3];
  const float* k_w  = (const float*)d_in[4];
  const float* k_b  = (const float*)d_in[5];
  const float* v_w  = (const float*)d_in[6];
  const float* v_b  = (const float*)d_in[7];
  const float* o_w  = (const float*)d_in[8];
  const float* o_b  = (const float*)d_in[9];
  const float* ln1w = (const float*)d_in[10];
  const float* ln1b = (const float*)d_in[11];
  const float* f1w  = (const float*)d_in[12];
  const float* f1b  = (const float*)d_in[13];
  const float* f2w  = (const float*)d_in[14];
  const float* f2b  = (const float*)d_in[15];
  const float* ln2w = (const float*)d_in[16];
  const float* ln2b = (const float*)d_in[17];

  unsigned short* WQ   = (unsigned short*)d_ws;        // 3x 1048576 contiguous = fused B
  unsigned short* WK   = WQ + 1048576;
  unsigned short* WV   = WK + 1048576;
  unsigned short* WO   = WV + 1048576;
  unsigned short* WF1  = WO + 1048576;                 // 4194304
  unsigned short* WF2  = WF1 + 4194304;                // 4194304
  unsigned short* ABUF = WF2 + 4194304;                // 7340032 (mem rows 0..1023, xn rows 1024..7167)
  unsigned short* QB   = ABUF + 7340032;               // 6291456 [n][384][64]; KB/VB at KOFF/VOFF
  unsigned short* KB   = QB + 6291456;                 // 7340032 [n][448][64]
  unsigned short* VB   = KB + 7340032;                 // 7340032 [n][448][64]
  unsigned short* VT   = VB + 7340032;                 // 7340032 [n][64][448]
  unsigned short* ATTN = VT + 7340032;                 // 6291456
  float*          X2   = (float*)(ATTN + 6291456);     // 6291456 f32
  float*          QKVB = (float*)ATTN;                 // 3072 f32, dead before attn writes ATTN
  unsigned short* XN2  = ATTN;                         // alias (attn dead after out-proj)
  unsigned short* HB   = ABUF;                         // alias (A/q/k/v staging dead after attention)

  // weight + memory converts (0.125 q-scale folded into weights+bias)
  cvt_bf16<<<1024, 256, 0, stream>>>(q_w, WQ, 262144, 0.125f);
  cvt_bf16<<<1024, 256, 0, stream>>>(k_w, WK, 262144, 1.f);
  cvt_bf16<<<1024, 256, 0, stream>>>(v_w, WV, 262144, 1.f);
  cvt_bf16<<<1024, 256, 0, stream>>>(o_w, WO, 262144, 1.f);
  cvt_bf16<<<4096, 256, 0, stream>>>(f1w, WF1, 1048576, 1.f);
  cvt_bf16<<<4096, 256, 0, stream>>>(f2w, WF2, 1048576, 1.f);
  cvt_bf16<<<1024, 256, 0, stream>>>(mem, ABUF, 262144, 1.f);
  concat_bias<<<12, 256, 0, stream>>>(q_b, k_b, v_b, QKVB);

  // LN1 -> xn (rows 1024.. of ABUF)
  ln_bf16<0><<<6144, 256, 0, stream>>>(x, ABUF + 1048576, ln1w, ln1b, nullptr, nullptr);

  // fused QKV: [mem;xn] x [Wq;Wk;Wv]^T, head-major epilogue (summary row is dead code)
  gemm_bt<5><<<dim3(24, 56), 256, 0, stream>>>(ABUF, WQ, QKVB, nullptr, QB, 7168, 3072, 1024, 1024, 1024);

  vtrans<<<dim3(7, 256), 256, 0, stream>>>(VB, VT);
  attn_kernel<<<6144, 64, 0, stream>>>(QB, KB, VT, ATTN);

  // out-proj + residual -> X2 (f32)
  gemm_bt<2><<<dim3(8, 48), 256, 0, stream>>>(ATTN, WO, o_b, x, X2, 6144, 1024, 1024, 1024, 1024);

  // LN2 -> xn2, and prefill d_out = X2 + fc2_bias (for split-K atomic fc2)
  ln_bf16<1><<<6144, 256, 0, stream>>>(X2, XN2, ln2w, ln2b, f2b, (float*)d_out);

  // FFN
  gemm_bt<3><<<dim3(32, 48), 256, 0, stream>>>(XN2, WF1, f1b, nullptr, HB, 6144, 4096, 1024, 1024, 1024);
  // fc2 split-K=2 in ONE dispatch (grid.z): 768 concurrent blocks, atomics into prefilled d_out
  gemm_bt<6><<<dim3(8, 48, 2), 256, 0, stream>>>(HB, WF2, nullptr, nullptr, d_out, 6144, 1024, 2048, 4096, 4096);
}

// Round 6
// 541.353 us; speedup vs baseline: 1.1015x; 1.0692x over previous
//
#include <hip/hip_runtime.h>

// ---------------- types / helpers ----------------
typedef __bf16 bf16x8 __attribute__((ext_vector_type(8)));
typedef float f32x4 __attribute__((ext_vector_type(4)));
typedef unsigned short u16x8 __attribute__((ext_vector_type(8)));

__device__ __forceinline__ unsigned short f2bf(float f) {
  union { float f; unsigned int u; } v; v.f = f;
  unsigned int r = v.u + 0x7fffu + ((v.u >> 16) & 1u);  // RNE
  return (unsigned short)(r >> 16);
}

__device__ __forceinline__ void async16(const unsigned short* g, unsigned short* l) {
  __builtin_amdgcn_global_load_lds(
      (const __attribute__((address_space(1))) unsigned int*)g,
      (__attribute__((address_space(3))) unsigned int*)l, 16, 0, 0);
}

// ---------------- f32 -> bf16 convert (optional scale) ----------------
__global__ void cvt_bf16(const float* __restrict__ s, unsigned short* __restrict__ d, int n4,
                         float scale) {
  int i = blockIdx.x * 256 + threadIdx.x;
  if (i >= n4) return;
  float4 v = ((const float4*)s)[i];
  ushort4 o;
  o.x = f2bf(v.x * scale); o.y = f2bf(v.y * scale);
  o.z = f2bf(v.z * scale); o.w = f2bf(v.w * scale);
  ((ushort4*)d)[i] = o;
}

// ---------------- QKV bias concat (q pre-scaled) ----------------
__global__ void concat_bias(const float* __restrict__ qb, const float* __restrict__ kb,
                            const float* __restrict__ vb, float* __restrict__ o) {
  int i = blockIdx.x * 256 + threadIdx.x;  // 3072
  float v = (i < 1024) ? qb[i] * 0.125f : (i < 2048 ? kb[i - 1024] : vb[i - 2048]);
  o[i] = v;
}

// ---------------- LayerNorm (per 1024-row) -> bf16 ----------------
// PREFILL: also write dout[row] = src[row] + fbias (fc2 bias), for split-K atomic fc2.
template <int PREFILL>
__global__ __launch_bounds__(256) void ln_bf16(
    const float* __restrict__ src, unsigned short* __restrict__ dst,
    const float* __restrict__ g, const float* __restrict__ be,
    const float* __restrict__ fbias, float* __restrict__ dout) {
  const int row = blockIdx.x, tid = threadIdx.x;
  const float4 v = ((const float4*)(src + (size_t)row * 1024))[tid];
  if (PREFILL) {
    const float4 fb = ((const float4*)fbias)[tid];
    float4 r;
    r.x = v.x + fb.x; r.y = v.y + fb.y; r.z = v.z + fb.z; r.w = v.w + fb.w;
    ((float4*)(dout + (size_t)row * 1024))[tid] = r;
  }
  float s = v.x + v.y + v.z + v.w;
  float qq = v.x * v.x + v.y * v.y + v.z * v.z + v.w * v.w;
#pragma unroll
  for (int off = 32; off; off >>= 1) { s += __shfl_xor(s, off); qq += __shfl_xor(qq, off); }
  __shared__ float ps[4], pq[4];
  const int w = tid >> 6, lane = tid & 63;
  if (lane == 0) { ps[w] = s; pq[w] = qq; }
  __syncthreads();
  if (tid == 0) { ps[0] = ps[0] + ps[1] + ps[2] + ps[3]; pq[0] = pq[0] + pq[1] + pq[2] + pq[3]; }
  __syncthreads();
  const float mu = ps[0] * (1.f / 1024.f);
  const float var = pq[0] * (1.f / 1024.f) - mu * mu;
  const float rs = rsqrtf(var + 1e-5f);
  const float4 gv = ((const float4*)g)[tid];
  const float4 bv = ((const float4*)be)[tid];
  ushort4 o;
  o.x = f2bf((v.x - mu) * rs * gv.x + bv.x);
  o.y = f2bf((v.y - mu) * rs * gv.y + bv.y);
  o.z = f2bf((v.z - mu) * rs * gv.z + bv.z);
  o.w = f2bf((v.w - mu) * rs * gv.w + bv.w);
  ((ushort4*)(dst + (size_t)row * 1024))[tid] = o;
}

// ---------------- GEMM: C[M,N] = A[M,K] @ B[N,K]^T (+ bias), m97-style ----------------
// EPI: 2 = acc+bias+resid -> f32 ; 3 = relu(acc+bias) -> bf16 ;
//      5 = fused QKV epilogue -> head-major bf16 (Cout = QB base; K/V at fixed offsets) ;
//      6 = atomicAdd(Cout, acc) f32 (split-K partial via blockIdx.z, bias pre-applied elsewhere)
#define KOFF 6291456ull
#define VOFF 13631488ull
template <int EPI>
__global__ __launch_bounds__(256) void gemm_bt(
    const unsigned short* __restrict__ A, const unsigned short* __restrict__ Bw,
    const float* __restrict__ bias, const float* __restrict__ resid,
    void* __restrict__ Cout, int M, int N, int K, int lda, int ldb) {
  __shared__ __align__(16) unsigned short lA[128 * 32];
  __shared__ __align__(16) unsigned short lB[128 * 32];
  const int tid = threadIdx.x;
  const int w = tid >> 6, lane = tid & 63;
  const int lr = lane & 15, lq = lane >> 4;
  const int bm = blockIdx.y, bn = blockIdx.x;
  const size_t koff = (size_t)blockIdx.z * K;  // split-K offset (z=0 when gridDim.z==1)
  const unsigned short* Ab = A + (size_t)bm * 128 * lda + koff;
  const unsigned short* Bb = Bw + (size_t)bn * 128 * ldb + koff;
  const int wm = (w & 1) << 6, wn = (w >> 1) << 6;
  f32x4 acc[4][4] = {};
  const int kiters = K >> 5;
  const int c0 = tid, c1 = 256 + tid;
  const int r0 = c0 >> 2, o0 = (c0 & 3) << 3;
  const int r1 = c1 >> 2, o1 = (c1 & 3) << 3;
  for (int kt = 0; kt < kiters; ++kt) {
    const int kb = kt << 5;
    __syncthreads();
    async16(Ab + (size_t)r0 * lda + kb + o0, lA + c0 * 8);
    async16(Bb + (size_t)r0 * ldb + kb + o0, lB + c0 * 8);
    async16(Ab + (size_t)r1 * lda + kb + o1, lA + c1 * 8);
    async16(Bb + (size_t)r1 * ldb + kb + o1, lB + c1 * 8);
    __syncthreads();
    bf16x8 af[4], bfr[4];
#pragma unroll
    for (int i = 0; i < 4; ++i) af[i] = *(const bf16x8*)(lA + (wm + i * 16 + lr) * 32 + lq * 8);
#pragma unroll
    for (int i = 0; i < 4; ++i) bfr[i] = *(const bf16x8*)(lB + (wn + i * 16 + lr) * 32 + lq * 8);
#pragma unroll
    for (int i = 0; i < 4; ++i)
#pragma unroll
      for (int j = 0; j < 4; ++j)
        acc[i][j] = __builtin_amdgcn_mfma_f32_16x16x32_bf16(af[i], bfr[j], acc[i][j], 0, 0, 0);
  }
  const int which = (bn * 128) >> 10;  // EPI5: 0=Q,1=K,2=V (block-uniform; 1024%128==0)
#pragma unroll
  for (int i = 0; i < 4; ++i) {
#pragma unroll
    for (int j = 0; j < 4; ++j) {
      const int colg = bn * 128 + wn + j * 16 + lr;
      const float bi = (EPI == 6) ? 0.f : bias[colg];
      const int rowg0 = bm * 128 + wm + i * 16 + lq * 4;
#pragma unroll
      for (int r = 0; r < 4; ++r) {
        const int rowg = rowg0 + r;
        const float val = acc[i][j][r] + bi;
        if (EPI == 5) {
          const int t = rowg >> 4, bb = rowg & 15;
          const int hh = (colg >> 6) & 15, dd = colg & 63;
          const size_t nn = (size_t)(bb * 16 + hh);
          unsigned short* q16 = (unsigned short*)Cout;
          if (which == 0) {
            if (rowg >= 1024) q16[(nn * 384 + (t - 64)) * 64 + dd] = f2bf(val);
          } else if (which == 1) {
            q16[KOFF + (nn * 448 + t) * 64 + dd] = f2bf(val);
          } else {
            q16[VOFF + (nn * 448 + t) * 64 + dd] = f2bf(val);
          }
        } else {
          const size_t idx = (size_t)rowg * N + colg;
          if (EPI == 2) ((float*)Cout)[idx] = val + resid[idx];
          else if (EPI == 3) ((unsigned short*)Cout)[idx] = f2bf(fmaxf(val, 0.f));
          else if (EPI == 6) atomicAdd(&((float*)Cout)[idx], acc[i][j][r]);
        }
      }
    }
  }
}

// ---------------- V transpose: vb[n][t][d] -> vt[n][d][t] ----------------
__global__ __launch_bounds__(256) void vtrans(const unsigned short* __restrict__ vb,
                                              unsigned short* __restrict__ vt) {
  __shared__ __align__(16) unsigned short ls[64][80];
  const int kc = blockIdx.x, n = blockIdx.y;
  const int tid = threadIdx.x;
#pragma unroll
  for (int i = 0; i < 2; ++i) {
    const int c = i * 256 + tid;
    const int kk = c >> 3, dc = (c & 7) << 3;
    u16x8 val = *(const u16x8*)(vb + ((size_t)n * 448 + kc * 64 + kk) * 64 + dc);
    *(u16x8*)&ls[kk][dc] = val;
  }
  __syncthreads();
#pragma unroll
  for (int i = 0; i < 2; ++i) {
    const int c = i * 256 + tid;
    const int d = c >> 3, kx = (c & 7) << 3;
    u16x8 o;
#pragma unroll
    for (int j = 0; j < 8; ++j) o[j] = ls[kx + j][d];
    *(u16x8*)(vt + ((size_t)n * 64 + d) * 448 + kc * 64 + kx) = o;
  }
}

// ---------------- fused attention, S^T formulation, 4 waves/block ----------------
// Block = 256 thr (4 waves) per (head, 16 q-rows). Wave w owns k-tiles [w*7, w*7+7):
// acc[7] = 28 VGPRs (vs 112 in r5's single-wave shape -> loads can pipeline, occupancy up).
// Row reductions: in-register over 7x4 + shuffles (xor 16,32) + 4-scalar cross-wave LDS combine.
#define PST 468  // P row stride (u16): dword stride 234 == 10 mod 32 -> ~2-way (free)
__global__ __launch_bounds__(256) void attn_kernel(
    const unsigned short* __restrict__ qt_, const unsigned short* __restrict__ kt_,
    const unsigned short* __restrict__ vt_, unsigned short* __restrict__ attn) {
  __shared__ __align__(16) unsigned short P[16 * PST];  // 14976 B
  __shared__ float Rm[4][16], Rs[4][16], Rc[4][16], Rv[4][16], R2[4][16];
  __shared__ __align__(16) float OT[4][16][17];         // per-wave transpose buffers
  const int id = blockIdx.x;
  const int xcd = id & 7, j0 = id >> 3;
  const int n = xcd * 32 + (j0 & 31), qt = j0 >> 5;  // qt 0..23
  const int b = n >> 4, h = n & 15;
  const int tid = threadIdx.x, w = tid >> 6, lane = tid & 63;
  const int lr = lane & 15, lq = lane >> 4;

  // Q fragments (B-operand; same rows for all 4 waves)
  const unsigned short* qp = qt_ + ((size_t)n * 384 + qt * 16 + lr) * 64 + lq * 8;
  const bf16x8 q0 = *(const bf16x8*)qp;
  const bf16x8 q1 = *(const bf16x8*)(qp + 32);

  // phase 1: S^T for 7 k-tiles. acc[t][r] = S[q=lr][k = (w*7+t)*16 + 4*lq + r]
  f32x4 acc[7];
#pragma unroll
  for (int t = 0; t < 7; ++t) {
    const unsigned short* kp = kt_ + ((size_t)n * 448 + (w * 7 + t) * 16 + lr) * 64 + lq * 8;
    const bf16x8 k0 = *(const bf16x8*)kp;
    const bf16x8 k1 = *(const bf16x8*)(kp + 32);
    f32x4 a = {0.f, 0.f, 0.f, 0.f};
    a = __builtin_amdgcn_mfma_f32_16x16x32_bf16(k0, q0, a, 0, 0, 0);
    a = __builtin_amdgcn_mfma_f32_16x16x32_bf16(k1, q1, a, 0, 0, 0);
    acc[t] = a;
  }

  // ---- pass 1: row max ----
  f32x4 m4 = acc[0];
#pragma unroll
  for (int t = 1; t < 7; ++t) {
    m4[0] = fmaxf(m4[0], acc[t][0]); m4[1] = fmaxf(m4[1], acc[t][1]);
    m4[2] = fmaxf(m4[2], acc[t][2]); m4[3] = fmaxf(m4[3], acc[t][3]);
  }
  float m = fmaxf(fmaxf(m4[0], m4[1]), fmaxf(m4[2], m4[3]));
  m = fmaxf(m, __shfl_xor(m, 16));
  m = fmaxf(m, __shfl_xor(m, 32));
  if (lq == 0) Rm[w][lr] = m;
  __syncthreads();
  m = fmaxf(fmaxf(Rm[0][lr], Rm[1][lr]), fmaxf(Rm[2][lr], Rm[3][lr]));

  // ---- exp in place; pass 2: sum + nonzero count ----
  f32x4 s4 = {0.f, 0.f, 0.f, 0.f}, c4 = {0.f, 0.f, 0.f, 0.f};
#pragma unroll
  for (int t = 0; t < 7; ++t) {
#pragma unroll
    for (int r = 0; r < 4; ++r) {
      const float e = __expf(acc[t][r] - m);
      acc[t][r] = e;
      s4[r] += e;
      if (e > 0.f) c4[r] += 1.f;
    }
  }
  float s = (s4[0] + s4[1]) + (s4[2] + s4[3]);
  float cnt = (c4[0] + c4[1]) + (c4[2] + c4[3]);
  s += __shfl_xor(s, 16); s += __shfl_xor(s, 32);
  cnt += __shfl_xor(cnt, 16); cnt += __shfl_xor(cnt, 32);
  if (lq == 0) { Rs[w][lr] = s; Rc[w][lr] = cnt; }
  __syncthreads();
  s = (Rs[0][lr] + Rs[1][lr]) + (Rs[2][lr] + Rs[3][lr]);
  cnt = (Rc[0][lr] + Rc[1][lr]) + (Rc[2][lr] + Rc[3][lr]);
  const float inv = 1.f / s;
  const float mean = 1.f / cnt;  // sum(p) == 1

  // ---- pass 3: variance of p over nonzeros ----
  f32x4 d4 = {0.f, 0.f, 0.f, 0.f};
#pragma unroll
  for (int t = 0; t < 7; ++t) {
#pragma unroll
    for (int r = 0; r < 4; ++r) {
      const float p = acc[t][r] * inv;
      const float dd = p - mean;
      if (acc[t][r] > 0.f) d4[r] += dd * dd;
    }
  }
  float dv = (d4[0] + d4[1]) + (d4[2] + d4[3]);
  dv += __shfl_xor(dv, 16); dv += __shfl_xor(dv, 32);
  if (lq == 0) Rv[w][lr] = dv;
  __syncthreads();
  dv = (Rv[0][lr] + Rv[1][lr]) + (Rv[2][lr] + Rv[3][lr]);
  const float thr = mean - 0.5f * sqrtf(dv / (cnt - 1.f));

  // ---- pass 4: survivor renormalizer (row max always survives: p_max >= mean >= thr) ----
  f32x4 t4 = {0.f, 0.f, 0.f, 0.f};
#pragma unroll
  for (int t = 0; t < 7; ++t) {
#pragma unroll
    for (int r = 0; r < 4; ++r) {
      if (!(acc[t][r] * inv < thr)) t4[r] += acc[t][r];
    }
  }
  float s2 = (t4[0] + t4[1]) + (t4[2] + t4[3]);
  s2 += __shfl_xor(s2, 16); s2 += __shfl_xor(s2, 32);
  if (lq == 0) R2[w][lr] = s2;
  __syncthreads();
  s2 = (R2[0][lr] + R2[1][lr]) + (R2[2][lr] + R2[3][lr]);
  const float inv2 = 1.f / s2;

  // ---- write P[q=lr][k] bf16 (wave w covers k in [w*112, w*112+112)) ----
#pragma unroll
  for (int t = 0; t < 7; ++t) {
#pragma unroll
    for (int rp = 0; rp < 4; rp += 2) {
      const float v0 = (acc[t][rp] * inv < thr) ? 0.f : acc[t][rp] * inv2;
      const float v1 = (acc[t][rp + 1] * inv < thr) ? 0.f : acc[t][rp + 1] * inv2;
      const unsigned int u = (unsigned int)f2bf(v0) | ((unsigned int)f2bf(v1) << 16);
      *(unsigned int*)&P[lr * PST + (w * 7 + t) * 16 + lq * 4 + rp] = u;
    }
  }
  __syncthreads();

  // phase 3: out^T[d][q] = V^T(64x448) . P(448x16). Wave w owns d-tile [w*16, w*16+16).
  f32x4 o = {0.f, 0.f, 0.f, 0.f};
#pragma unroll
  for (int c = 0; c < 14; ++c) {
    union { ushort4 hh[2]; bf16x8 v; } bf;
    bf.hh[0] = *(const ushort4*)&P[lr * PST + c * 32 + lq * 8];
    bf.hh[1] = *(const ushort4*)&P[lr * PST + c * 32 + lq * 8 + 4];
    const bf16x8 a = *(const bf16x8*)(vt_ + ((size_t)n * 64 + w * 16 + lr) * 448 + c * 32 + lq * 8);
    o = __builtin_amdgcn_mfma_f32_16x16x32_bf16(a, bf.v, o, 0, 0, 0);
  }

  // transpose 16x16 tile via wave-private LDS (no barrier: same-wave write->read)
#pragma unroll
  for (int r = 0; r < 4; ++r) OT[w][lq * 4 + r][lr] = o[r];
  const int qrow = lane >> 2, dg = lane & 3;
  ushort4 ov;
  ov.x = f2bf(OT[w][dg * 4 + 0][qrow]);
  ov.y = f2bf(OT[w][dg * 4 + 1][qrow]);
  ov.z = f2bf(OT[w][dg * 4 + 2][qrow]);
  ov.w = f2bf(OT[w][dg * 4 + 3][qrow]);
  *(ushort4*)(attn + ((size_t)(qt * 16 + qrow) * 16 + b) * 1024 + h * 64 + w * 16 + dg * 4) = ov;
}

// ---------------- launch ----------------
extern "C" void kernel_launch(void* const* d_in, const int* in_sizes, int n_in,
                              void* d_out, int out_size, void* d_ws, size_t ws_size,
                              hipStream_t stream) {
  (void)in_sizes; (void)n_in; (void)out_size; (void)ws_size;
  const float* x    = (const float*)d_in[0];
  const float* mem  = (const float*)d_in[1];
  const float* q_w  = (const float*)d_in[2];
  const float* q_b  = (const float*)d_in[3];
  const float* k_w  = (const float*)d_in[4];
  const float* k_b  = (const float*)d_in[5];
  const float* v_w  = (const float*)d_in[6];
  const float* v_b  = (const float*)d_in[7];
  const float* o_w  = (const float*)d_in[8];
  const float* o_b  = (const float*)d_in[9];
  const float* ln1w = (const float*)d_in[10];
  const float* ln1b = (const float*)d_in[11];
  const float* f1w  = (const float*)d_in[12];
  const float* f1b  = (const float*)d_in[13];
  const float* f2w  = (const float*)d_in[14];
  const float* f2b  = (const float*)d_in[15];
  const float* ln2w = (const float*)d_in[16];
  const float* ln2b = (const float*)d_in[17];

  unsigned short* WQ   = (unsigned short*)d_ws;        // 3x 1048576 contiguous = fused B
  unsigned short* WK   = WQ + 1048576;
  unsigned short* WV   = WK + 1048576;
  unsigned short* WO   = WV + 1048576;
  unsigned short* WF1  = WO + 1048576;                 // 4194304
  unsigned short* WF2  = WF1 + 4194304;                // 4194304
  unsigned short* ABUF = WF2 + 4194304;                // 7340032 (mem rows 0..1023, xn rows 1024..7167)
  unsigned short* QB   = ABUF + 7340032;               // 6291456 [n][384][64]; KB/VB at KOFF/VOFF
  unsigned short* KB   = QB + 6291456;                 // 7340032 [n][448][64]
  unsigned short* VB   = KB + 7340032;                 // 7340032 [n][448][64]
  unsigned short* VT   = VB + 7340032;                 // 7340032 [n][64][448]
  unsigned short* ATTN = VT + 7340032;                 // 6291456
  float*          X2   = (float*)(ATTN + 6291456);     // 6291456 f32
  float*          QKVB = (float*)ATTN;                 // 3072 f32, dead before attn writes ATTN
  unsigned short* XN2  = ATTN;                         // alias (attn dead after out-proj)
  unsigned short* HB   = ABUF;                         // alias (A/q/k/v staging dead after attention)

  // weight + memory converts (0.125 q-scale folded into weights+bias)
  cvt_bf16<<<1024, 256, 0, stream>>>(q_w, WQ, 262144, 0.125f);
  cvt_bf16<<<1024, 256, 0, stream>>>(k_w, WK, 262144, 1.f);
  cvt_bf16<<<1024, 256, 0, stream>>>(v_w, WV, 262144, 1.f);
  cvt_bf16<<<1024, 256, 0, stream>>>(o_w, WO, 262144, 1.f);
  cvt_bf16<<<4096, 256, 0, stream>>>(f1w, WF1, 1048576, 1.f);
  cvt_bf16<<<4096, 256, 0, stream>>>(f2w, WF2, 1048576, 1.f);
  cvt_bf16<<<1024, 256, 0, stream>>>(mem, ABUF, 262144, 1.f);
  concat_bias<<<12, 256, 0, stream>>>(q_b, k_b, v_b, QKVB);

  // LN1 -> xn (rows 1024.. of ABUF)
  ln_bf16<0><<<6144, 256, 0, stream>>>(x, ABUF + 1048576, ln1w, ln1b, nullptr, nullptr);

  // fused QKV: [mem;xn] x [Wq;Wk;Wv]^T, head-major epilogue (summary row is dead code)
  gemm_bt<5><<<dim3(24, 56), 256, 0, stream>>>(ABUF, WQ, QKVB, nullptr, QB, 7168, 3072, 1024, 1024, 1024);

  vtrans<<<dim3(7, 256), 256, 0, stream>>>(VB, VT);
  attn_kernel<<<6144, 256, 0, stream>>>(QB, KB, VT, ATTN);

  // out-proj + residual -> X2 (f32)
  gemm_bt<2><<<dim3(8, 48), 256, 0, stream>>>(ATTN, WO, o_b, x, X2, 6144, 1024, 1024, 1024, 1024);

  // LN2 -> xn2, and prefill d_out = X2 + fc2_bias (for split-K atomic fc2)
  ln_bf16<1><<<6144, 256, 0, stream>>>(X2, XN2, ln2w, ln2b, f2b, (float*)d_out);

  // FFN
  gemm_bt<3><<<dim3(32, 48), 256, 0, stream>>>(XN2, WF1, f1b, nullptr, HB, 6144, 4096, 1024, 1024, 1024);
  // fc2 split-K=2 in ONE dispatch (grid.z): 768 concurrent blocks, atomics into prefilled d_out
  gemm_bt<6><<<dim3(8, 48, 2), 256, 0, stream>>>(HB, WF2, nullptr, nullptr, d_out, 6144, 1024, 2048, 4096, 4096);
}

// Round 7
// 530.059 us; speedup vs baseline: 1.1250x; 1.0213x over previous
//
#include <hip/hip_runtime.h>

// ---------------- types / helpers ----------------
typedef __bf16 bf16x8 __attribute__((ext_vector_type(8)));
typedef float f32x4 __attribute__((ext_vector_type(4)));
typedef unsigned short u16x8 __attribute__((ext_vector_type(8)));

__device__ __forceinline__ unsigned short f2bf(float f) {
  union { float f; unsigned int u; } v; v.f = f;
  unsigned int r = v.u + 0x7fffu + ((v.u >> 16) & 1u);  // RNE
  return (unsigned short)(r >> 16);
}

__device__ __forceinline__ void async16(const unsigned short* g, unsigned short* l) {
  __builtin_amdgcn_global_load_lds(
      (const __attribute__((address_space(1))) unsigned int*)g,
      (__attribute__((address_space(3))) unsigned int*)l, 16, 0, 0);
}

// ---------------- fused converts: all weights + memory + bias concat, ONE launch ------
__global__ void cvt_all(const float* __restrict__ q_w, const float* __restrict__ k_w,
                        const float* __restrict__ v_w, const float* __restrict__ o_w,
                        const float* __restrict__ f1w, const float* __restrict__ f2w,
                        const float* __restrict__ mem,
                        const float* __restrict__ q_b, const float* __restrict__ k_b,
                        const float* __restrict__ v_b,
                        unsigned short* __restrict__ WQ, unsigned short* __restrict__ WK,
                        unsigned short* __restrict__ WV, unsigned short* __restrict__ WO,
                        unsigned short* __restrict__ WF1, unsigned short* __restrict__ WF2,
                        unsigned short* __restrict__ MEMB, float* __restrict__ QKVB) {
  const int bid = blockIdx.x;
  const float* src; unsigned short* dst; float scale = 1.f; int base;
  if (bid < 1024)       { src = q_w; dst = WQ;  scale = 0.125f; base = 0; }
  else if (bid < 2048)  { src = k_w; dst = WK;  base = 1024; }
  else if (bid < 3072)  { src = v_w; dst = WV;  base = 2048; }
  else if (bid < 4096)  { src = o_w; dst = WO;  base = 3072; }
  else if (bid < 8192)  { src = f1w; dst = WF1; base = 4096; }
  else if (bid < 12288) { src = f2w; dst = WF2; base = 8192; }
  else if (bid < 13312) { src = mem; dst = MEMB; base = 12288; }
  else {  // bias concat (12 blocks, 3072 elems), q-bias pre-scaled
    const int i = (bid - 13312) * 256 + threadIdx.x;
    QKVB[i] = (i < 1024) ? q_b[i] * 0.125f : (i < 2048 ? k_b[i - 1024] : v_b[i - 2048]);
    return;
  }
  const int i = (bid - base) * 256 + threadIdx.x;
  float4 v = ((const float4*)src)[i];
  ushort4 o;
  o.x = f2bf(v.x * scale); o.y = f2bf(v.y * scale);
  o.z = f2bf(v.z * scale); o.w = f2bf(v.w * scale);
  ((ushort4*)dst)[i] = o;
}

// ---------------- LayerNorm (per 1024-row) -> bf16 ----------------
// PREFILL: also write dout[row] = src[row] + fbias (fc2 bias), for split-K atomic fc2.
template <int PREFILL>
__global__ __launch_bounds__(256) void ln_bf16(
    const float* __restrict__ src, unsigned short* __restrict__ dst,
    const float* __restrict__ g, const float* __restrict__ be,
    const float* __restrict__ fbias, float* __restrict__ dout) {
  const int row = blockIdx.x, tid = threadIdx.x;
  const float4 v = ((const float4*)(src + (size_t)row * 1024))[tid];
  if (PREFILL) {
    const float4 fb = ((const float4*)fbias)[tid];
    float4 r;
    r.x = v.x + fb.x; r.y = v.y + fb.y; r.z = v.z + fb.z; r.w = v.w + fb.w;
    ((float4*)(dout + (size_t)row * 1024))[tid] = r;
  }
  float s = v.x + v.y + v.z + v.w;
  float qq = v.x * v.x + v.y * v.y + v.z * v.z + v.w * v.w;
#pragma unroll
  for (int off = 32; off; off >>= 1) { s += __shfl_xor(s, off); qq += __shfl_xor(qq, off); }
  __shared__ float ps[4], pq[4];
  const int w = tid >> 6, lane = tid & 63;
  if (lane == 0) { ps[w] = s; pq[w] = qq; }
  __syncthreads();
  if (tid == 0) { ps[0] = ps[0] + ps[1] + ps[2] + ps[3]; pq[0] = pq[0] + pq[1] + pq[2] + pq[3]; }
  __syncthreads();
  const float mu = ps[0] * (1.f / 1024.f);
  const float var = pq[0] * (1.f / 1024.f) - mu * mu;
  const float rs = rsqrtf(var + 1e-5f);
  const float4 gv = ((const float4*)g)[tid];
  const float4 bv = ((const float4*)be)[tid];
  ushort4 o;
  o.x = f2bf((v.x - mu) * rs * gv.x + bv.x);
  o.y = f2bf((v.y - mu) * rs * gv.y + bv.y);
  o.z = f2bf((v.z - mu) * rs * gv.z + bv.z);
  o.w = f2bf((v.w - mu) * rs * gv.w + bv.w);
  ((ushort4*)(dst + (size_t)row * 1024))[tid] = o;
}

// ---------------- GEMM: C[M,N] = A[M,K] @ B[N,K]^T (+ bias), m97-style ----------------
// 1D grid with XCD swizzle: l&7 = XCD; each XCD owns bn-stripe of width W (B-weights
// L2-resident), bn cycles fastest within an XCD so A-tiles stay hot for W blocks.
// EPI: 2 = acc+bias+resid -> f32 ; 3 = relu(acc+bias) -> bf16 ;
//      5 = fused QKV epilogue -> head-major bf16 (Cout = QB base; K/V at fixed offsets) ;
//      6 = atomicAdd(Cout, acc) f32 (split-K partial via z, bias pre-applied elsewhere)
#define KOFF 6291456ull
#define VOFF 13631488ull
template <int EPI>
__global__ __launch_bounds__(256) void gemm_bt(
    const unsigned short* __restrict__ A, const unsigned short* __restrict__ Bw,
    const float* __restrict__ bias, const float* __restrict__ resid,
    void* __restrict__ Cout, int M, int N, int K, int lda, int ldb, int NBM, int W) {
  __shared__ __align__(16) unsigned short lA[128 * 32];
  __shared__ __align__(16) unsigned short lB[128 * 32];
  const int tid = threadIdx.x;
  const int w = tid >> 6, lane = tid & 63;
  const int lr = lane & 15, lq = lane >> 4;
  const int l = blockIdx.x;
  const int xcd = l & 7, r = l >> 3;
  const int bn = xcd * W + (r % W);
  const int rest = r / W;
  const int bm = rest % NBM;
  const size_t koff = (size_t)(rest / NBM) * K;  // split-K offset
  const unsigned short* Ab = A + (size_t)bm * 128 * lda + koff;
  const unsigned short* Bb = Bw + (size_t)bn * 128 * ldb + koff;
  const int wm = (w & 1) << 6, wn = (w >> 1) << 6;
  f32x4 acc[4][4] = {};
  const int kiters = K >> 5;
  const int c0 = tid, c1 = 256 + tid;
  const int r0 = c0 >> 2, o0 = (c0 & 3) << 3;
  const int r1 = c1 >> 2, o1 = (c1 & 3) << 3;
  for (int kt = 0; kt < kiters; ++kt) {
    const int kb = kt << 5;
    __syncthreads();
    async16(Ab + (size_t)r0 * lda + kb + o0, lA + c0 * 8);
    async16(Bb + (size_t)r0 * ldb + kb + o0, lB + c0 * 8);
    async16(Ab + (size_t)r1 * lda + kb + o1, lA + c1 * 8);
    async16(Bb + (size_t)r1 * ldb + kb + o1, lB + c1 * 8);
    __syncthreads();
    bf16x8 af[4], bfr[4];
#pragma unroll
    for (int i = 0; i < 4; ++i) af[i] = *(const bf16x8*)(lA + (wm + i * 16 + lr) * 32 + lq * 8);
#pragma unroll
    for (int i = 0; i < 4; ++i) bfr[i] = *(const bf16x8*)(lB + (wn + i * 16 + lr) * 32 + lq * 8);
#pragma unroll
    for (int i = 0; i < 4; ++i)
#pragma unroll
      for (int j = 0; j < 4; ++j)
        acc[i][j] = __builtin_amdgcn_mfma_f32_16x16x32_bf16(af[i], bfr[j], acc[i][j], 0, 0, 0);
  }
  const int which = (bn * 128) >> 10;  // EPI5: 0=Q,1=K,2=V (block-uniform; 1024%128==0)
#pragma unroll
  for (int i = 0; i < 4; ++i) {
#pragma unroll
    for (int j = 0; j < 4; ++j) {
      const int colg = bn * 128 + wn + j * 16 + lr;
      const float bi = (EPI == 6) ? 0.f : bias[colg];
      const int rowg0 = bm * 128 + wm + i * 16 + lq * 4;
#pragma unroll
      for (int r2 = 0; r2 < 4; ++r2) {
        const int rowg = rowg0 + r2;
        const float val = acc[i][j][r2] + bi;
        if (EPI == 5) {
          const int t = rowg >> 4, bb = rowg & 15;
          const int hh = (colg >> 6) & 15, dd = colg & 63;
          const size_t nn = (size_t)(bb * 16 + hh);
          unsigned short* q16 = (unsigned short*)Cout;
          if (which == 0) {
            if (rowg >= 1024) q16[(nn * 384 + (t - 64)) * 64 + dd] = f2bf(val);
          } else if (which == 1) {
            q16[KOFF + (nn * 448 + t) * 64 + dd] = f2bf(val);
          } else {
            q16[VOFF + (nn * 448 + t) * 64 + dd] = f2bf(val);
          }
        } else {
          const size_t idx = (size_t)rowg * N + colg;
          if (EPI == 2) ((float*)Cout)[idx] = val + resid[idx];
          else if (EPI == 3) ((unsigned short*)Cout)[idx] = f2bf(fmaxf(val, 0.f));
          else if (EPI == 6) atomicAdd(&((float*)Cout)[idx], acc[i][j][r2]);
        }
      }
    }
  }
}

// ---------------- V transpose: vb[n][t][d] -> vt[n][d][t] ----------------
__global__ __launch_bounds__(256) void vtrans(const unsigned short* __restrict__ vb,
                                              unsigned short* __restrict__ vt) {
  __shared__ __align__(16) unsigned short ls[64][80];
  const int kc = blockIdx.x, n = blockIdx.y;
  const int tid = threadIdx.x;
#pragma unroll
  for (int i = 0; i < 2; ++i) {
    const int c = i * 256 + tid;
    const int kk = c >> 3, dc = (c & 7) << 3;
    u16x8 val = *(const u16x8*)(vb + ((size_t)n * 448 + kc * 64 + kk) * 64 + dc);
    *(u16x8*)&ls[kk][dc] = val;
  }
  __syncthreads();
#pragma unroll
  for (int i = 0; i < 2; ++i) {
    const int c = i * 256 + tid;
    const int d = c >> 3, kx = (c & 7) << 3;
    u16x8 o;
#pragma unroll
    for (int j = 0; j < 8; ++j) o[j] = ls[kx + j][d];
    *(u16x8*)(vt + ((size_t)n * 64 + d) * 448 + kc * 64 + kx) = o;
  }
}

// ---------------- fused attention, S^T formulation, 4 waves/block ----------------
#define PST 468  // P row stride (u16): dword stride 234 == 10 mod 32 -> ~2-way (free)
__global__ __launch_bounds__(256) void attn_kernel(
    const unsigned short* __restrict__ qt_, const unsigned short* __restrict__ kt_,
    const unsigned short* __restrict__ vt_, unsigned short* __restrict__ attn) {
  __shared__ __align__(16) unsigned short P[16 * PST];  // 14976 B
  __shared__ float Rm[4][16], Rs[4][16], Rc[4][16], Rv[4][16], R2[4][16];
  __shared__ __align__(16) float OT[4][16][17];         // per-wave transpose buffers
  const int id = blockIdx.x;
  const int xcd = id & 7, j0 = id >> 3;
  const int n = xcd * 32 + (j0 & 31), qt = j0 >> 5;  // qt 0..23
  const int b = n >> 4, h = n & 15;
  const int tid = threadIdx.x, w = tid >> 6, lane = tid & 63;
  const int lr = lane & 15, lq = lane >> 4;

  const unsigned short* qp = qt_ + ((size_t)n * 384 + qt * 16 + lr) * 64 + lq * 8;
  const bf16x8 q0 = *(const bf16x8*)qp;
  const bf16x8 q1 = *(const bf16x8*)(qp + 32);

  // phase 1: S^T for 7 k-tiles. acc[t][r] = S[q=lr][k = (w*7+t)*16 + 4*lq + r]
  f32x4 acc[7];
#pragma unroll
  for (int t = 0; t < 7; ++t) {
    const unsigned short* kp = kt_ + ((size_t)n * 448 + (w * 7 + t) * 16 + lr) * 64 + lq * 8;
    const bf16x8 k0 = *(const bf16x8*)kp;
    const bf16x8 k1 = *(const bf16x8*)(kp + 32);
    f32x4 a = {0.f, 0.f, 0.f, 0.f};
    a = __builtin_amdgcn_mfma_f32_16x16x32_bf16(k0, q0, a, 0, 0, 0);
    a = __builtin_amdgcn_mfma_f32_16x16x32_bf16(k1, q1, a, 0, 0, 0);
    acc[t] = a;
  }

  // ---- pass 1: row max ----
  f32x4 m4 = acc[0];
#pragma unroll
  for (int t = 1; t < 7; ++t) {
    m4[0] = fmaxf(m4[0], acc[t][0]); m4[1] = fmaxf(m4[1], acc[t][1]);
    m4[2] = fmaxf(m4[2], acc[t][2]); m4[3] = fmaxf(m4[3], acc[t][3]);
  }
  float m = fmaxf(fmaxf(m4[0], m4[1]), fmaxf(m4[2], m4[3]));
  m = fmaxf(m, __shfl_xor(m, 16));
  m = fmaxf(m, __shfl_xor(m, 32));
  if (lq == 0) Rm[w][lr] = m;
  __syncthreads();
  m = fmaxf(fmaxf(Rm[0][lr], Rm[1][lr]), fmaxf(Rm[2][lr], Rm[3][lr]));

  // ---- exp in place; pass 2: sum + nonzero count ----
  f32x4 s4 = {0.f, 0.f, 0.f, 0.f}, c4 = {0.f, 0.f, 0.f, 0.f};
#pragma unroll
  for (int t = 0; t < 7; ++t) {
#pragma unroll
    for (int r = 0; r < 4; ++r) {
      const float e = __expf(acc[t][r] - m);
      acc[t][r] = e;
      s4[r] += e;
      if (e > 0.f) c4[r] += 1.f;
    }
  }
  float s = (s4[0] + s4[1]) + (s4[2] + s4[3]);
  float cnt = (c4[0] + c4[1]) + (c4[2] + c4[3]);
  s += __shfl_xor(s, 16); s += __shfl_xor(s, 32);
  cnt += __shfl_xor(cnt, 16); cnt += __shfl_xor(cnt, 32);
  if (lq == 0) { Rs[w][lr] = s; Rc[w][lr] = cnt; }
  __syncthreads();
  s = (Rs[0][lr] + Rs[1][lr]) + (Rs[2][lr] + Rs[3][lr]);
  cnt = (Rc[0][lr] + Rc[1][lr]) + (Rc[2][lr] + Rc[3][lr]);
  const float inv = 1.f / s;
  const float mean = 1.f / cnt;  // sum(p) == 1

  // ---- pass 3: variance of p over nonzeros ----
  f32x4 d4 = {0.f, 0.f, 0.f, 0.f};
#pragma unroll
  for (int t = 0; t < 7; ++t) {
#pragma unroll
    for (int r = 0; r < 4; ++r) {
      const float p = acc[t][r] * inv;
      const float dd = p - mean;
      if (acc[t][r] > 0.f) d4[r] += dd * dd;
    }
  }
  float dv = (d4[0] + d4[1]) + (d4[2] + d4[3]);
  dv += __shfl_xor(dv, 16); dv += __shfl_xor(dv, 32);
  if (lq == 0) Rv[w][lr] = dv;
  __syncthreads();
  dv = (Rv[0][lr] + Rv[1][lr]) + (Rv[2][lr] + Rv[3][lr]);
  const float thr = mean - 0.5f * sqrtf(dv / (cnt - 1.f));

  // ---- pass 4: survivor renormalizer (row max always survives: p_max >= mean >= thr) ----
  f32x4 t4 = {0.f, 0.f, 0.f, 0.f};
#pragma unroll
  for (int t = 0; t < 7; ++t) {
#pragma unroll
    for (int r = 0; r < 4; ++r) {
      if (!(acc[t][r] * inv < thr)) t4[r] += acc[t][r];
    }
  }
  float s2 = (t4[0] + t4[1]) + (t4[2] + t4[3]);
  s2 += __shfl_xor(s2, 16); s2 += __shfl_xor(s2, 32);
  if (lq == 0) R2[w][lr] = s2;
  __syncthreads();
  s2 = (R2[0][lr] + R2[1][lr]) + (R2[2][lr] + R2[3][lr]);
  const float inv2 = 1.f / s2;

  // ---- write P[q=lr][k] bf16 (wave w covers k in [w*112, w*112+112)) ----
#pragma unroll
  for (int t = 0; t < 7; ++t) {
#pragma unroll
    for (int rp = 0; rp < 4; rp += 2) {
      const float v0 = (acc[t][rp] * inv < thr) ? 0.f : acc[t][rp] * inv2;
      const float v1 = (acc[t][rp + 1] * inv < thr) ? 0.f : acc[t][rp + 1] * inv2;
      const unsigned int u = (unsigned int)f2bf(v0) | ((unsigned int)f2bf(v1) << 16);
      *(unsigned int*)&P[lr * PST + (w * 7 + t) * 16 + lq * 4 + rp] = u;
    }
  }
  __syncthreads();

  // phase 3: out^T[d][q] = V^T(64x448) . P(448x16). Wave w owns d-tile [w*16, w*16+16).
  f32x4 o = {0.f, 0.f, 0.f, 0.f};
#pragma unroll
  for (int c = 0; c < 14; ++c) {
    union { ushort4 hh[2]; bf16x8 v; } bf;
    bf.hh[0] = *(const ushort4*)&P[lr * PST + c * 32 + lq * 8];
    bf.hh[1] = *(const ushort4*)&P[lr * PST + c * 32 + lq * 8 + 4];
    const bf16x8 a = *(const bf16x8*)(vt_ + ((size_t)n * 64 + w * 16 + lr) * 448 + c * 32 + lq * 8);
    o = __builtin_amdgcn_mfma_f32_16x16x32_bf16(a, bf.v, o, 0, 0, 0);
  }

  // transpose 16x16 tile via wave-private LDS (no barrier: same-wave write->read)
#pragma unroll
  for (int r = 0; r < 4; ++r) OT[w][lq * 4 + r][lr] = o[r];
  const int qrow = lane >> 2, dg = lane & 3;
  ushort4 ov;
  ov.x = f2bf(OT[w][dg * 4 + 0][qrow]);
  ov.y = f2bf(OT[w][dg * 4 + 1][qrow]);
  ov.z = f2bf(OT[w][dg * 4 + 2][qrow]);
  ov.w = f2bf(OT[w][dg * 4 + 3][qrow]);
  *(ushort4*)(attn + ((size_t)(qt * 16 + qrow) * 16 + b) * 1024 + h * 64 + w * 16 + dg * 4) = ov;
}

// ---------------- launch ----------------
extern "C" void kernel_launch(void* const* d_in, const int* in_sizes, int n_in,
                              void* d_out, int out_size, void* d_ws, size_t ws_size,
                              hipStream_t stream) {
  (void)in_sizes; (void)n_in; (void)out_size; (void)ws_size;
  const float* x    = (const float*)d_in[0];
  const float* mem  = (const float*)d_in[1];
  const float* q_w  = (const float*)d_in[2];
  const float* q_b  = (const float*)d_in[3];
  const float* k_w  = (const float*)d_in[4];
  const float* k_b  = (const float*)d_in[5];
  const float* v_w  = (const float*)d_in[6];
  const float* v_b  = (const float*)d_in[7];
  const float* o_w  = (const float*)d_in[8];
  const float* o_b  = (const float*)d_in[9];
  const float* ln1w = (const float*)d_in[10];
  const float* ln1b = (const float*)d_in[11];
  const float* f1w  = (const float*)d_in[12];
  const float* f1b  = (const float*)d_in[13];
  const float* f2w  = (const float*)d_in[14];
  const float* f2b  = (const float*)d_in[15];
  const float* ln2w = (const float*)d_in[16];
  const float* ln2b = (const float*)d_in[17];

  unsigned short* WQ   = (unsigned short*)d_ws;        // 3x 1048576 contiguous = fused B
  unsigned short* WK   = WQ + 1048576;
  unsigned short* WV   = WK + 1048576;
  unsigned short* WO   = WV + 1048576;
  unsigned short* WF1  = WO + 1048576;                 // 4194304
  unsigned short* WF2  = WF1 + 4194304;                // 4194304
  unsigned short* ABUF = WF2 + 4194304;                // 7340032 (mem rows 0..1023, xn rows 1024..7167)
  unsigned short* QB   = ABUF + 7340032;               // 6291456 [n][384][64]; KB/VB at KOFF/VOFF
  unsigned short* KB   = QB + 6291456;                 // 7340032 [n][448][64]
  unsigned short* VB   = KB + 7340032;                 // 7340032 [n][448][64]
  unsigned short* VT   = VB + 7340032;                 // 7340032 [n][64][448]
  unsigned short* ATTN = VT + 7340032;                 // 6291456
  float*          X2   = (float*)(ATTN + 6291456);     // 6291456 f32
  float*          QKVB = (float*)ATTN;                 // 3072 f32, dead before attn writes ATTN
  unsigned short* XN2  = ATTN;                         // alias (attn dead after out-proj)
  unsigned short* HB   = ABUF;                         // alias (A/q/k/v staging dead after attention)

  // all weight/memory converts + bias concat in ONE launch
  cvt_all<<<13324, 256, 0, stream>>>(q_w, k_w, v_w, o_w, f1w, f2w, mem, q_b, k_b, v_b,
                                     WQ, WK, WV, WO, WF1, WF2, ABUF, QKVB);

  // LN1 -> xn (rows 1024.. of ABUF)
  ln_bf16<0><<<6144, 256, 0, stream>>>(x, ABUF + 1048576, ln1w, ln1b, nullptr, nullptr);

  // fused QKV: [mem;xn] x [Wq;Wk;Wv]^T, head-major epilogue. NBN=24 -> W=3.
  gemm_bt<5><<<1344, 256, 0, stream>>>(ABUF, WQ, QKVB, nullptr, QB, 7168, 3072, 1024, 1024, 1024, 56, 3);

  vtrans<<<dim3(7, 256), 256, 0, stream>>>(VB, VT);
  attn_kernel<<<6144, 256, 0, stream>>>(QB, KB, VT, ATTN);

  // out-proj + residual -> X2 (f32). NBN=8 -> W=1.
  gemm_bt<2><<<384, 256, 0, stream>>>(ATTN, WO, o_b, x, X2, 6144, 1024, 1024, 1024, 1024, 48, 1);

  // LN2 -> xn2, and prefill d_out = X2 + fc2_bias (for split-K atomic fc2)
  ln_bf16<1><<<6144, 256, 0, stream>>>(X2, XN2, ln2w, ln2b, f2b, (float*)d_out);

  // FFN. fc1: NBN=32 -> W=4. fc2: NBN=8 -> W=1, split-K=2 (rest/NBM = z).
  gemm_bt<3><<<1536, 256, 0, stream>>>(XN2, WF1, f1b, nullptr, HB, 6144, 4096, 1024, 1024, 1024, 48, 4);
  gemm_bt<6><<<768, 256, 0, stream>>>(HB, WF2, nullptr, nullptr, d_out, 6144, 1024, 2048, 4096, 4096, 48, 1);
}

// Round 8
// 523.526 us; speedup vs baseline: 1.1390x; 1.0125x over previous
//
#include <hip/hip_runtime.h>

// ---------------- types / helpers ----------------
typedef __bf16 bf16x8 __attribute__((ext_vector_type(8)));
typedef float f32x4 __attribute__((ext_vector_type(4)));
typedef unsigned short u16x8 __attribute__((ext_vector_type(8)));

__device__ __forceinline__ unsigned short f2bf(float f) {
  union { float f; unsigned int u; } v; v.f = f;
  unsigned int r = v.u + 0x7fffu + ((v.u >> 16) & 1u);  // RNE
  return (unsigned short)(r >> 16);
}

__device__ __forceinline__ void async16(const unsigned short* g, unsigned short* l) {
  __builtin_amdgcn_global_load_lds(
      (const __attribute__((address_space(1))) unsigned int*)g,
      (__attribute__((address_space(3))) unsigned int*)l, 16, 0, 0);
}

// ---------------- fused converts: all weights + memory + bias concat, ONE launch ------
__global__ void cvt_all(const float* __restrict__ q_w, const float* __restrict__ k_w,
                        const float* __restrict__ v_w, const float* __restrict__ o_w,
                        const float* __restrict__ f1w, const float* __restrict__ f2w,
                        const float* __restrict__ mem,
                        const float* __restrict__ q_b, const float* __restrict__ k_b,
                        const float* __restrict__ v_b,
                        unsigned short* __restrict__ WQ, unsigned short* __restrict__ WK,
                        unsigned short* __restrict__ WV, unsigned short* __restrict__ WO,
                        unsigned short* __restrict__ WF1, unsigned short* __restrict__ WF2,
                        unsigned short* __restrict__ MEMB, float* __restrict__ QKVB) {
  const int bid = blockIdx.x;
  const float* src; unsigned short* dst; float scale = 1.f; int base;
  if (bid < 1024)       { src = q_w; dst = WQ;  scale = 0.125f; base = 0; }
  else if (bid < 2048)  { src = k_w; dst = WK;  base = 1024; }
  else if (bid < 3072)  { src = v_w; dst = WV;  base = 2048; }
  else if (bid < 4096)  { src = o_w; dst = WO;  base = 3072; }
  else if (bid < 8192)  { src = f1w; dst = WF1; base = 4096; }
  else if (bid < 12288) { src = f2w; dst = WF2; base = 8192; }
  else if (bid < 13312) { src = mem; dst = MEMB; base = 12288; }
  else {  // bias concat (12 blocks, 3072 elems), q-bias pre-scaled
    const int i = (bid - 13312) * 256 + threadIdx.x;
    QKVB[i] = (i < 1024) ? q_b[i] * 0.125f : (i < 2048 ? k_b[i - 1024] : v_b[i - 2048]);
    return;
  }
  const int i = (bid - base) * 256 + threadIdx.x;
  float4 v = ((const float4*)src)[i];
  ushort4 o;
  o.x = f2bf(v.x * scale); o.y = f2bf(v.y * scale);
  o.z = f2bf(v.z * scale); o.w = f2bf(v.w * scale);
  ((ushort4*)dst)[i] = o;
}

// ---------------- LayerNorm (per 1024-row) -> bf16 ----------------
// PREFILL: also write dout[row] = src[row] + fbias (fc2 bias), for split-K atomic fc2.
template <int PREFILL>
__global__ __launch_bounds__(256) void ln_bf16(
    const float* __restrict__ src, unsigned short* __restrict__ dst,
    const float* __restrict__ g, const float* __restrict__ be,
    const float* __restrict__ fbias, float* __restrict__ dout) {
  const int row = blockIdx.x, tid = threadIdx.x;
  const float4 v = ((const float4*)(src + (size_t)row * 1024))[tid];
  if (PREFILL) {
    const float4 fb = ((const float4*)fbias)[tid];
    float4 r;
    r.x = v.x + fb.x; r.y = v.y + fb.y; r.z = v.z + fb.z; r.w = v.w + fb.w;
    ((float4*)(dout + (size_t)row * 1024))[tid] = r;
  }
  float s = v.x + v.y + v.z + v.w;
  float qq = v.x * v.x + v.y * v.y + v.z * v.z + v.w * v.w;
#pragma unroll
  for (int off = 32; off; off >>= 1) { s += __shfl_xor(s, off); qq += __shfl_xor(qq, off); }
  __shared__ float ps[4], pq[4];
  const int w = tid >> 6, lane = tid & 63;
  if (lane == 0) { ps[w] = s; pq[w] = qq; }
  __syncthreads();
  if (tid == 0) { ps[0] = ps[0] + ps[1] + ps[2] + ps[3]; pq[0] = pq[0] + pq[1] + pq[2] + pq[3]; }
  __syncthreads();
  const float mu = ps[0] * (1.f / 1024.f);
  const float var = pq[0] * (1.f / 1024.f) - mu * mu;
  const float rs = rsqrtf(var + 1e-5f);
  const float4 gv = ((const float4*)g)[tid];
  const float4 bv = ((const float4*)be)[tid];
  ushort4 o;
  o.x = f2bf((v.x - mu) * rs * gv.x + bv.x);
  o.y = f2bf((v.y - mu) * rs * gv.y + bv.y);
  o.z = f2bf((v.z - mu) * rs * gv.z + bv.z);
  o.w = f2bf((v.w - mu) * rs * gv.w + bv.w);
  ((ushort4*)(dst + (size_t)row * 1024))[tid] = o;
}

// ---------------- GEMM: C[M,N] = A[M,K] @ B[N,K]^T (+ bias), m97-style ----------------
// 1D grid, XCD swizzle striping the LARGE operand (A/activations): l&7 = XCD;
// bm = xcd*WM + (r%WM) -> per-XCD A-stripe is 1.6-6.3 MB (L2-resident);
// bn = (r/WM)%NBN streams the small B (weights) once per XCD.
// (r7 lesson: bn-striping made each XCD stream ALL of A -> fc2 FETCH 205 MB.)
// EPI: 2 = acc+bias+resid -> f32 ; 3 = relu(acc+bias) -> bf16 ;
//      5 = fused QKV epilogue -> head-major bf16 (Cout = QB base; K/V at fixed offsets) ;
//      6 = atomicAdd(Cout, acc) f32 (split-K partial via z, bias pre-applied elsewhere)
#define KOFF 6291456ull
#define VOFF 13631488ull
template <int EPI>
__global__ __launch_bounds__(256) void gemm_bt(
    const unsigned short* __restrict__ A, const unsigned short* __restrict__ Bw,
    const float* __restrict__ bias, const float* __restrict__ resid,
    void* __restrict__ Cout, int M, int N, int K, int lda, int ldb, int NBN, int WM) {
  __shared__ __align__(16) unsigned short lA[128 * 32];
  __shared__ __align__(16) unsigned short lB[128 * 32];
  const int tid = threadIdx.x;
  const int w = tid >> 6, lane = tid & 63;
  const int lr = lane & 15, lq = lane >> 4;
  const int l = blockIdx.x;
  const int xcd = l & 7, r = l >> 3;
  const int bm = xcd * WM + (r % WM);
  const int rest = r / WM;
  const int bn = rest % NBN;
  const size_t koff = (size_t)(rest / NBN) * K;  // split-K offset
  const unsigned short* Ab = A + (size_t)bm * 128 * lda + koff;
  const unsigned short* Bb = Bw + (size_t)bn * 128 * ldb + koff;
  const int wm = (w & 1) << 6, wn = (w >> 1) << 6;
  f32x4 acc[4][4] = {};
  const int kiters = K >> 5;
  const int c0 = tid, c1 = 256 + tid;
  const int r0 = c0 >> 2, o0 = (c0 & 3) << 3;
  const int r1 = c1 >> 2, o1 = (c1 & 3) << 3;
  for (int kt = 0; kt < kiters; ++kt) {
    const int kb = kt << 5;
    __syncthreads();
    async16(Ab + (size_t)r0 * lda + kb + o0, lA + c0 * 8);
    async16(Bb + (size_t)r0 * ldb + kb + o0, lB + c0 * 8);
    async16(Ab + (size_t)r1 * lda + kb + o1, lA + c1 * 8);
    async16(Bb + (size_t)r1 * ldb + kb + o1, lB + c1 * 8);
    __syncthreads();
    bf16x8 af[4], bfr[4];
#pragma unroll
    for (int i = 0; i < 4; ++i) af[i] = *(const bf16x8*)(lA + (wm + i * 16 + lr) * 32 + lq * 8);
#pragma unroll
    for (int i = 0; i < 4; ++i) bfr[i] = *(const bf16x8*)(lB + (wn + i * 16 + lr) * 32 + lq * 8);
#pragma unroll
    for (int i = 0; i < 4; ++i)
#pragma unroll
      for (int j = 0; j < 4; ++j)
        acc[i][j] = __builtin_amdgcn_mfma_f32_16x16x32_bf16(af[i], bfr[j], acc[i][j], 0, 0, 0);
  }
  const int which = (bn * 128) >> 10;  // EPI5: 0=Q,1=K,2=V (block-uniform; 1024%128==0)
#pragma unroll
  for (int i = 0; i < 4; ++i) {
#pragma unroll
    for (int j = 0; j < 4; ++j) {
      const int colg = bn * 128 + wn + j * 16 + lr;
      const float bi = (EPI == 6) ? 0.f : bias[colg];
      const int rowg0 = bm * 128 + wm + i * 16 + lq * 4;
#pragma unroll
      for (int r2 = 0; r2 < 4; ++r2) {
        const int rowg = rowg0 + r2;
        const float val = acc[i][j][r2] + bi;
        if (EPI == 5) {
          const int t = rowg >> 4, bb = rowg & 15;
          const int hh = (colg >> 6) & 15, dd = colg & 63;
          const size_t nn = (size_t)(bb * 16 + hh);
          unsigned short* q16 = (unsigned short*)Cout;
          if (which == 0) {
            if (rowg >= 1024) q16[(nn * 384 + (t - 64)) * 64 + dd] = f2bf(val);
          } else if (which == 1) {
            q16[KOFF + (nn * 448 + t) * 64 + dd] = f2bf(val);
          } else {
            q16[VOFF + (nn * 448 + t) * 64 + dd] = f2bf(val);
          }
        } else {
          const size_t idx = (size_t)rowg * N + colg;
          if (EPI == 2) ((float*)Cout)[idx] = val + resid[idx];
          else if (EPI == 3) ((unsigned short*)Cout)[idx] = f2bf(fmaxf(val, 0.f));
          else if (EPI == 6) atomicAdd(&((float*)Cout)[idx], acc[i][j][r2]);
        }
      }
    }
  }
}

// ---------------- V transpose: vb[n][t][d] -> vt[n][d][t] ----------------
__global__ __launch_bounds__(256) void vtrans(const unsigned short* __restrict__ vb,
                                              unsigned short* __restrict__ vt) {
  __shared__ __align__(16) unsigned short ls[64][80];
  const int kc = blockIdx.x, n = blockIdx.y;
  const int tid = threadIdx.x;
#pragma unroll
  for (int i = 0; i < 2; ++i) {
    const int c = i * 256 + tid;
    const int kk = c >> 3, dc = (c & 7) << 3;
    u16x8 val = *(const u16x8*)(vb + ((size_t)n * 448 + kc * 64 + kk) * 64 + dc);
    *(u16x8*)&ls[kk][dc] = val;
  }
  __syncthreads();
#pragma unroll
  for (int i = 0; i < 2; ++i) {
    const int c = i * 256 + tid;
    const int d = c >> 3, kx = (c & 7) << 3;
    u16x8 o;
#pragma unroll
    for (int j = 0; j < 8; ++j) o[j] = ls[kx + j][d];
    *(u16x8*)(vt + ((size_t)n * 64 + d) * 448 + kc * 64 + kx) = o;
  }
}

// ---------------- fused attention, S^T formulation, 4 waves/block ----------------
#define PST 468  // P row stride (u16): dword stride 234 == 10 mod 32 -> ~2-way (free)
__global__ __launch_bounds__(256) void attn_kernel(
    const unsigned short* __restrict__ qt_, const unsigned short* __restrict__ kt_,
    const unsigned short* __restrict__ vt_, unsigned short* __restrict__ attn) {
  __shared__ __align__(16) unsigned short P[16 * PST];  // 14976 B
  __shared__ float Rm[4][16], Rs[4][16], Rc[4][16], Rv[4][16], R2[4][16];
  __shared__ __align__(16) float OT[4][16][17];         // per-wave transpose buffers
  const int id = blockIdx.x;
  const int xcd = id & 7, j0 = id >> 3;
  const int n = xcd * 32 + (j0 & 31), qt = j0 >> 5;  // qt 0..23
  const int b = n >> 4, h = n & 15;
  const int tid = threadIdx.x, w = tid >> 6, lane = tid & 63;
  const int lr = lane & 15, lq = lane >> 4;

  const unsigned short* qp = qt_ + ((size_t)n * 384 + qt * 16 + lr) * 64 + lq * 8;
  const bf16x8 q0 = *(const bf16x8*)qp;
  const bf16x8 q1 = *(const bf16x8*)(qp + 32);

  // phase 1: S^T for 7 k-tiles. acc[t][r] = S[q=lr][k = (w*7+t)*16 + 4*lq + r]
  f32x4 acc[7];
#pragma unroll
  for (int t = 0; t < 7; ++t) {
    const unsigned short* kp = kt_ + ((size_t)n * 448 + (w * 7 + t) * 16 + lr) * 64 + lq * 8;
    const bf16x8 k0 = *(const bf16x8*)kp;
    const bf16x8 k1 = *(const bf16x8*)(kp + 32);
    f32x4 a = {0.f, 0.f, 0.f, 0.f};
    a = __builtin_amdgcn_mfma_f32_16x16x32_bf16(k0, q0, a, 0, 0, 0);
    a = __builtin_amdgcn_mfma_f32_16x16x32_bf16(k1, q1, a, 0, 0, 0);
    acc[t] = a;
  }

  // ---- pass 1: row max ----
  f32x4 m4 = acc[0];
#pragma unroll
  for (int t = 1; t < 7; ++t) {
    m4[0] = fmaxf(m4[0], acc[t][0]); m4[1] = fmaxf(m4[1], acc[t][1]);
    m4[2] = fmaxf(m4[2], acc[t][2]); m4[3] = fmaxf(m4[3], acc[t][3]);
  }
  float m = fmaxf(fmaxf(m4[0], m4[1]), fmaxf(m4[2], m4[3]));
  m = fmaxf(m, __shfl_xor(m, 16));
  m = fmaxf(m, __shfl_xor(m, 32));
  if (lq == 0) Rm[w][lr] = m;
  __syncthreads();
  m = fmaxf(fmaxf(Rm[0][lr], Rm[1][lr]), fmaxf(Rm[2][lr], Rm[3][lr]));

  // ---- exp in place; pass 2: sum + nonzero count ----
  f32x4 s4 = {0.f, 0.f, 0.f, 0.f}, c4 = {0.f, 0.f, 0.f, 0.f};
#pragma unroll
  for (int t = 0; t < 7; ++t) {
#pragma unroll
    for (int r = 0; r < 4; ++r) {
      const float e = __expf(acc[t][r] - m);
      acc[t][r] = e;
      s4[r] += e;
      if (e > 0.f) c4[r] += 1.f;
    }
  }
  float s = (s4[0] + s4[1]) + (s4[2] + s4[3]);
  float cnt = (c4[0] + c4[1]) + (c4[2] + c4[3]);
  s += __shfl_xor(s, 16); s += __shfl_xor(s, 32);
  cnt += __shfl_xor(cnt, 16); cnt += __shfl_xor(cnt, 32);
  if (lq == 0) { Rs[w][lr] = s; Rc[w][lr] = cnt; }
  __syncthreads();
  s = (Rs[0][lr] + Rs[1][lr]) + (Rs[2][lr] + Rs[3][lr]);
  cnt = (Rc[0][lr] + Rc[1][lr]) + (Rc[2][lr] + Rc[3][lr]);
  const float inv = 1.f / s;
  const float mean = 1.f / cnt;  // sum(p) == 1

  // ---- pass 3: variance of p over nonzeros ----
  f32x4 d4 = {0.f, 0.f, 0.f, 0.f};
#pragma unroll
  for (int t = 0; t < 7; ++t) {
#pragma unroll
    for (int r = 0; r < 4; ++r) {
      const float p = acc[t][r] * inv;
      const float dd = p - mean;
      if (acc[t][r] > 0.f) d4[r] += dd * dd;
    }
  }
  float dv = (d4[0] + d4[1]) + (d4[2] + d4[3]);
  dv += __shfl_xor(dv, 16); dv += __shfl_xor(dv, 32);
  if (lq == 0) Rv[w][lr] = dv;
  __syncthreads();
  dv = (Rv[0][lr] + Rv[1][lr]) + (Rv[2][lr] + Rv[3][lr]);
  const float thr = mean - 0.5f * sqrtf(dv / (cnt - 1.f));

  // ---- pass 4: survivor renormalizer (row max always survives: p_max >= mean >= thr) ----
  f32x4 t4 = {0.f, 0.f, 0.f, 0.f};
#pragma unroll
  for (int t = 0; t < 7; ++t) {
#pragma unroll
    for (int r = 0; r < 4; ++r) {
      if (!(acc[t][r] * inv < thr)) t4[r] += acc[t][r];
    }
  }
  float s2 = (t4[0] + t4[1]) + (t4[2] + t4[3]);
  s2 += __shfl_xor(s2, 16); s2 += __shfl_xor(s2, 32);
  if (lq == 0) R2[w][lr] = s2;
  __syncthreads();
  s2 = (R2[0][lr] + R2[1][lr]) + (R2[2][lr] + R2[3][lr]);
  const float inv2 = 1.f / s2;

  // ---- write P[q=lr][k] bf16 (wave w covers k in [w*112, w*112+112)) ----
#pragma unroll
  for (int t = 0; t < 7; ++t) {
#pragma unroll
    for (int rp = 0; rp < 4; rp += 2) {
      const float v0 = (acc[t][rp] * inv < thr) ? 0.f : acc[t][rp] * inv2;
      const float v1 = (acc[t][rp + 1] * inv < thr) ? 0.f : acc[t][rp + 1] * inv2;
      const unsigned int u = (unsigned int)f2bf(v0) | ((unsigned int)f2bf(v1) << 16);
      *(unsigned int*)&P[lr * PST + (w * 7 + t) * 16 + lq * 4 + rp] = u;
    }
  }
  __syncthreads();

  // phase 3: out^T[d][q] = V^T(64x448) . P(448x16). Wave w owns d-tile [w*16, w*16+16).
  f32x4 o = {0.f, 0.f, 0.f, 0.f};
#pragma unroll
  for (int c = 0; c < 14; ++c) {
    union { ushort4 hh[2]; bf16x8 v; } bf;
    bf.hh[0] = *(const ushort4*)&P[lr * PST + c * 32 + lq * 8];
    bf.hh[1] = *(const ushort4*)&P[lr * PST + c * 32 + lq * 8 + 4];
    const bf16x8 a = *(const bf16x8*)(vt_ + ((size_t)n * 64 + w * 16 + lr) * 448 + c * 32 + lq * 8);
    o = __builtin_amdgcn_mfma_f32_16x16x32_bf16(a, bf.v, o, 0, 0, 0);
  }

  // transpose 16x16 tile via wave-private LDS (no barrier: same-wave write->read)
#pragma unroll
  for (int r = 0; r < 4; ++r) OT[w][lq * 4 + r][lr] = o[r];
  const int qrow = lane >> 2, dg = lane & 3;
  ushort4 ov;
  ov.x = f2bf(OT[w][dg * 4 + 0][qrow]);
  ov.y = f2bf(OT[w][dg * 4 + 1][qrow]);
  ov.z = f2bf(OT[w][dg * 4 + 2][qrow]);
  ov.w = f2bf(OT[w][dg * 4 + 3][qrow]);
  *(ushort4*)(attn + ((size_t)(qt * 16 + qrow) * 16 + b) * 1024 + h * 64 + w * 16 + dg * 4) = ov;
}

// ---------------- launch ----------------
extern "C" void kernel_launch(void* const* d_in, const int* in_sizes, int n_in,
                              void* d_out, int out_size, void* d_ws, size_t ws_size,
                              hipStream_t stream) {
  (void)in_sizes; (void)n_in; (void)out_size; (void)ws_size;
  const float* x    = (const float*)d_in[0];
  const float* mem  = (const float*)d_in[1];
  const float* q_w  = (const float*)d_in[2];
  const float* q_b  = (const float*)d_in[3];
  const float* k_w  = (const float*)d_in[4];
  const float* k_b  = (const float*)d_in[5];
  const float* v_w  = (const float*)d_in[6];
  const float* v_b  = (const float*)d_in[7];
  const float* o_w  = (const float*)d_in[8];
  const float* o_b  = (const float*)d_in[9];
  const float* ln1w = (const float*)d_in[10];
  const float* ln1b = (const float*)d_in[11];
  const float* f1w  = (const float*)d_in[12];
  const float* f1b  = (const float*)d_in[13];
  const float* f2w  = (const float*)d_in[14];
  const float* f2b  = (const float*)d_in[15];
  const float* ln2w = (const float*)d_in[16];
  const float* ln2b = (const float*)d_in[17];

  unsigned short* WQ   = (unsigned short*)d_ws;        // 3x 1048576 contiguous = fused B
  unsigned short* WK   = WQ + 1048576;
  unsigned short* WV   = WK + 1048576;
  unsigned short* WO   = WV + 1048576;
  unsigned short* WF1  = WO + 1048576;                 // 4194304
  unsigned short* WF2  = WF1 + 4194304;                // 4194304
  unsigned short* ABUF = WF2 + 4194304;                // 7340032 (mem rows 0..1023, xn rows 1024..7167)
  unsigned short* QB   = ABUF + 7340032;               // 6291456 [n][384][64]; KB/VB at KOFF/VOFF
  unsigned short* KB   = QB + 6291456;                 // 7340032 [n][448][64]
  unsigned short* VB   = KB + 7340032;                 // 7340032 [n][448][64]
  unsigned short* VT   = VB + 7340032;                 // 7340032 [n][64][448]
  unsigned short* ATTN = VT + 7340032;                 // 6291456
  float*          X2   = (float*)(ATTN + 6291456);     // 6291456 f32
  float*          QKVB = (float*)ATTN;                 // 3072 f32, dead before attn writes ATTN
  unsigned short* XN2  = ATTN;                         // alias (attn dead after out-proj)
  unsigned short* HB   = ABUF;                         // alias (A/q/k/v staging dead after attention)

  // all weight/memory converts + bias concat in ONE launch
  cvt_all<<<13324, 256, 0, stream>>>(q_w, k_w, v_w, o_w, f1w, f2w, mem, q_b, k_b, v_b,
                                     WQ, WK, WV, WO, WF1, WF2, ABUF, QKVB);

  // LN1 -> xn (rows 1024.. of ABUF)
  ln_bf16<0><<<6144, 256, 0, stream>>>(x, ABUF + 1048576, ln1w, ln1b, nullptr, nullptr);

  // fused QKV: [mem;xn] x [Wq;Wk;Wv]^T, head-major epilogue. NBM=56 -> WM=7, NBN=24.
  gemm_bt<5><<<1344, 256, 0, stream>>>(ABUF, WQ, QKVB, nullptr, QB, 7168, 3072, 1024, 1024, 1024, 24, 7);

  vtrans<<<dim3(7, 256), 256, 0, stream>>>(VB, VT);
  attn_kernel<<<6144, 256, 0, stream>>>(QB, KB, VT, ATTN);

  // out-proj + residual -> X2 (f32). NBM=48 -> WM=6, NBN=8.
  gemm_bt<2><<<384, 256, 0, stream>>>(ATTN, WO, o_b, x, X2, 6144, 1024, 1024, 1024, 1024, 8, 6);

  // LN2 -> xn2, and prefill d_out = X2 + fc2_bias (for split-K atomic fc2)
  ln_bf16<1><<<6144, 256, 0, stream>>>(X2, XN2, ln2w, ln2b, f2b, (float*)d_out);

  // FFN. fc1: WM=6, NBN=32. fc2: WM=6, NBN=8, split-K=2 (z = rest/NBN).
  gemm_bt<3><<<1536, 256, 0, stream>>>(XN2, WF1, f1b, nullptr, HB, 6144, 4096, 1024, 1024, 1024, 32, 6);
  gemm_bt<6><<<768, 256, 0, stream>>>(HB, WF2, nullptr, nullptr, d_out, 6144, 1024, 2048, 4096, 4096, 8, 6);
}